// Round 4
// baseline (915.006 us; speedup 1.0000x reference)
//
#include <hip/hip_runtime.h>
#include <hip/hip_bf16.h>

typedef __hip_bfloat16 bf16;

#define NB 16

// drug conv chain:  L 64 ->61(K4,C40) ->56(K6,C80) ->49(K8,C160)
// prot conv chain:  L 1200 ->1197(K4,C40) ->1190(K8,C80) ->1179(K12,C160)

__device__ __forceinline__ float b2f(bf16 x) { return __bfloat162float(x); }
__device__ __forceinline__ float u16bf(unsigned short u) {
    return __uint_as_float(((unsigned)u) << 16);
}
__device__ __forceinline__ unsigned short f2bu(float v) {
    union { bf16 h; unsigned short u; } cv;
    cv.h = __float2bfloat16(v);
    return cv.u;
}

// ---------------- dtype sniffer (bf16 vs f32 inputs) ----------------
__global__ void sniff_kernel(const unsigned short* __restrict__ w, int* __restrict__ flag) {
    __shared__ int cnt;
    if (threadIdx.x == 0) cnt = 0;
    __syncthreads();
    int hits = 0;
    for (int s = 0; s < 4; s++) {
        unsigned short u = w[(threadIdx.x * 4 + s) * 2];
        float v = fabsf(u16bf(u));
        if (v > 1e-6f && v < 2.0f) hits++;
    }
    atomicAdd(&cnt, hits);
    __syncthreads();
    if (threadIdx.x == 0) *flag = (cnt > 512) ? 1 : 0;
}

// ---------------- conversions ----------------
#define NSEG 15
struct CvtJob {
    const void* src[NSEG];
    float* dst[NSEG];
    int n[NSEG];
};

__global__ void megacvt(CvtJob job, const int* __restrict__ flagp) {
    int seg = blockIdx.y;
    int i = blockIdx.x * 256 + threadIdx.x;
    if (i >= job.n[seg]) return;
    float v = (*flagp) ? b2f(((const bf16*)job.src[seg])[i])
                       : ((const float*)job.src[seg])[i];
    job.dst[seg][i] = v;
}

// conv weights [Cout][CIN][K] -> f32 [ci*K+k][Cout]
__global__ void cvt_wT(const void* __restrict__ src, float* __restrict__ dst,
                       int Cout, int CK, const int* __restrict__ flagp) {
    int i = blockIdx.x * 256 + threadIdx.x;
    if (i >= Cout * CK) return;
    int co = i / CK, r = i - co * CK;
    float v = (*flagp) ? b2f(((const bf16*)src)[i]) : ((const float*)src)[i];
    dst[r * Cout + co] = v;
}

// [160,160] (o,c) -> f32 transposed [c*160+o], three matrices
__global__ void cvt160t(const void* s0, const void* s1, const void* s2,
                        float* d0, float* d1, float* d2, const int* __restrict__ flagp) {
    int i = blockIdx.x * 256 + threadIdx.x;
    if (i >= 25600) return;
    const void* s = blockIdx.y == 0 ? s0 : (blockIdx.y == 1 ? s1 : s2);
    float* d = blockIdx.y == 0 ? d0 : (blockIdx.y == 1 ? d1 : d2);
    int o = i / 160, c = i % 160;
    float v = (*flagp) ? b2f(((const bf16*)s)[i]) : ((const float*)s)[i];
    d[c * 160 + o] = v;
}

__global__ void zero_init(float* __restrict__ pair, float* __restrict__ Md) {
    int i = blockIdx.x * 256 + threadIdx.x;
    if (i < NB * 320) pair[i] = 0.f;
    if (i < NB * 49 * 160) Md[i] = 0.f;
}

// ---------------- conv v3: register-blocked, conflict-free LDS ----------------
// Thread li handles positions l0+li and l0+li+64 (stride-1 LDS reads, 2 lanes/
// bank = free). Staging: grid-stride over CIN*TLX with all 256 threads.
// grid (B*tilesL, Cout/(4*CPT)), block 256. Ltile = 128.
template <int CIN, int K, int CPT>
__global__ __launch_bounds__(256) void conv_v3(const bf16* __restrict__ x,
                                               const float* __restrict__ wT,
                                               const float* __restrict__ bias,
                                               bf16* __restrict__ y,
                                               int Lin, int Lout, int Cout, int tilesL) {
    const int TLX = 128 + K - 1;
    __shared__ float xs[CIN * TLX];
    int b = blockIdx.x / tilesL;
    int l0 = (blockIdx.x % tilesL) << 7;
    const bf16* xb = x + (size_t)b * CIN * Lin;
    for (int i = threadIdx.x; i < CIN * TLX; i += 256) {
        int ci = i / TLX, j = i - ci * TLX;
        int l = l0 + j;
        xs[i] = (l < Lin) ? b2f(xb[ci * Lin + l]) : 0.f;
    }
    __syncthreads();
    int li = threadIdx.x & 63;
    int cg = __builtin_amdgcn_readfirstlane(threadIdx.x >> 6);
    int co0 = (blockIdx.y * 4 + cg) * CPT;
    float acc0[CPT], acc1[CPT];
#pragma unroll
    for (int c = 0; c < CPT; c++) { acc0[c] = bias[co0 + c]; acc1[c] = acc0[c]; }
    for (int ci = 0; ci < CIN; ci++) {
        float xa[K], xb2[K];
        const float* xr = xs + ci * TLX + li;
#pragma unroll
        for (int t = 0; t < K; t++) { xa[t] = xr[t]; xb2[t] = xr[t + 64]; }
        const float* wr = wT + (size_t)(ci * K) * Cout + co0;
#pragma unroll
        for (int k = 0; k < K; k++) {
#pragma unroll
            for (int c = 0; c < CPT; c++) {
                float w = wr[k * Cout + c];
                acc0[c] += xa[k] * w;
                acc1[c] += xb2[k] * w;
            }
        }
    }
    int lA = l0 + li, lB = lA + 64;
    bool okA = (lA < Lout), okB = (lB < Lout);
#pragma unroll
    for (int c = 0; c < CPT; c++) {
        bf16* yr = y + ((size_t)b * Cout + co0 + c) * Lout;
        if (okA) yr[lA] = __float2bfloat16(fmaxf(acc0[c], 0.f));
        if (okB) yr[lB] = __float2bfloat16(fmaxf(acc1[c], 0.f));
    }
}

// conv1 fused with embedding gather (CIN=64, K=4, Cout=40, CPT=10)
__global__ __launch_bounds__(256) void conv1_embed(const int* __restrict__ tok,
                                                   const float* __restrict__ embF,
                                                   const float* __restrict__ wT,
                                                   const float* __restrict__ bias,
                                                   bf16* __restrict__ y,
                                                   int Lin, int Lout, int tilesL) {
    const int K = 4, CIN = 64, TLX = 131, CPT = 10, Cout = 40;
    __shared__ float xs[CIN * TLX];
    __shared__ int stok[TLX];
    int b = blockIdx.x / tilesL;
    int l0 = (blockIdx.x % tilesL) << 7;
    if (threadIdx.x < TLX) {
        int l = l0 + threadIdx.x;
        stok[threadIdx.x] = (l < Lin) ? tok[b * Lin + l] : -1;
    }
    __syncthreads();
    for (int i = threadIdx.x; i < CIN * TLX; i += 256) {
        int ci = i / TLX, j = i - ci * TLX;
        int t = stok[j];
        xs[i] = (t >= 0) ? embF[t * 64 + ci] : 0.f;
    }
    __syncthreads();
    int li = threadIdx.x & 63;
    int cg = __builtin_amdgcn_readfirstlane(threadIdx.x >> 6);
    int co0 = cg * CPT;
    float acc0[CPT], acc1[CPT];
#pragma unroll
    for (int c = 0; c < CPT; c++) { acc0[c] = bias[co0 + c]; acc1[c] = acc0[c]; }
    for (int ci = 0; ci < CIN; ci++) {
        float xa[K], xb2[K];
        const float* xr = xs + ci * TLX + li;
#pragma unroll
        for (int t = 0; t < K; t++) { xa[t] = xr[t]; xb2[t] = xr[t + 64]; }
        const float* wr = wT + (size_t)(ci * K) * Cout + co0;
#pragma unroll
        for (int k = 0; k < K; k++) {
#pragma unroll
            for (int c = 0; c < CPT; c++) {
                float w = wr[k * Cout + c];
                acc0[c] += xa[k] * w;
                acc1[c] += xb2[k] * w;
            }
        }
    }
    int lA = l0 + li, lB = lA + 64;
    bool okA = (lA < Lout), okB = (lB < Lout);
#pragma unroll
    for (int c = 0; c < CPT; c++) {
        bf16* yr = y + ((size_t)b * Cout + co0 + c) * Lout;
        if (okA) yr[lA] = __float2bfloat16(fmaxf(acc0[c], 0.f));
        if (okB) yr[lB] = __float2bfloat16(fmaxf(acc1[c], 0.f));
    }
}

// ---------------- attention projection ----------------
__device__ __forceinline__ void stv(float* p, float v) { *p = v; }
__device__ __forceinline__ void stv(bf16* p, float v) { *p = __float2bfloat16(v); }

template <typename OT>
__global__ __launch_bounds__(256) void att_proj(const bf16* __restrict__ x,
                                                const float* __restrict__ wt,
                                                const float* __restrict__ bias,
                                                OT* __restrict__ y, int L) {
    __shared__ float xs[160 * 64];
    int tilesL = (L + 63) >> 6;
    int b = blockIdx.x / tilesL;
    int l0 = (blockIdx.x % tilesL) << 6;
    const bf16* xb = x + (size_t)b * 160 * L;
    for (int i = threadIdx.x; i < 160 * 64; i += 256) {
        int c = i >> 6, j = i & 63;
        int l = l0 + j;
        xs[i] = (l < L) ? b2f(xb[c * L + l]) : 0.f;
    }
    __syncthreads();
    int li = threadIdx.x & 63;
    int og = __builtin_amdgcn_readfirstlane(threadIdx.x >> 6);
    int o0 = blockIdx.y * 40 + og * 10;
    float acc[10];
#pragma unroll
    for (int j = 0; j < 10; j++) acc[j] = bias[o0 + j];
    for (int c = 0; c < 160; c++) {
        float xv = xs[(c << 6) + li];
        const float* wr = wt + c * 160 + o0;
#pragma unroll
        for (int j = 0; j < 10; j++) acc[j] += xv * wr[j];
    }
    int l = l0 + li;
    if (l < L) {
        OT* yr = y + ((size_t)b * L + l) * 160 + o0;
#pragma unroll
        for (int j = 0; j < 10; j++) stv(yr + j, acc[j]);
    }
}

// ---------------- mean over d (49) -> Mp_t [b][160][1184] bf16 ----------------
#define MP_PITCH 1184
__global__ __launch_bounds__(192) void mean_p_kernel(const float* __restrict__ datt,
                                                     const bf16* __restrict__ patt,
                                                     bf16* __restrict__ MpT) {
    int b = blockIdx.x / 37;
    int p0 = (blockIdx.x % 37) * 32;
    int k = threadIdx.x;
    if (k >= 160) return;
    float dv[49];
#pragma unroll
    for (int d = 0; d < 49; d++) dv[d] = datt[((size_t)b * 49 + d) * 160 + k];
    float s[32];
#pragma unroll
    for (int pi = 0; pi < 32; pi++) {
        int p = p0 + pi;
        float acc = 0.f;
        if (p < 1179) {
            float pv = b2f(patt[((size_t)b * 1179 + p) * 160 + k]);
#pragma unroll
            for (int d = 0; d < 49; d++) acc += fmaxf(dv[d] + pv, 0.f);
        }
        s[pi] = acc * (1.f / 49.f);
    }
    unsigned short* row = (unsigned short*)MpT + ((size_t)b * 160 + k) * MP_PITCH + p0;
#pragma unroll
    for (int g = 0; g < 8; g++) {
        ushort4 u;
        u.x = f2bu(s[g * 4 + 0]); u.y = f2bu(s[g * 4 + 1]);
        u.z = f2bu(s[g * 4 + 2]); u.w = f2bu(s[g * 4 + 3]);
        *(ushort4*)(row + g * 4) = u;
    }
}

// ---------------- mean over p (1179) partial -> atomicAdd into Md f32 ----------------
__global__ __launch_bounds__(192) void mean_d_partial(const float* __restrict__ datt,
                                                      const bf16* __restrict__ patt,
                                                      float* __restrict__ Md) {
    int b = blockIdx.x;
    int ps = blockIdx.y;
    int k = threadIdx.x;
    if (k >= 160) return;
    int p0 = ps * 99, p1 = min(p0 + 99, 1179);
    float dv[49], acc[49];
#pragma unroll
    for (int d = 0; d < 49; d++) {
        dv[d] = datt[((size_t)b * 49 + d) * 160 + k];
        acc[d] = 0.f;
    }
    for (int p = p0; p < p1; p++) {
        float pv = b2f(patt[((size_t)b * 1179 + p) * 160 + k]);
#pragma unroll
        for (int d = 0; d < 49; d++) acc[d] += fmaxf(dv[d] + pv, 0.f);
    }
#pragma unroll
    for (int d = 0; d < 49; d++)
        atomicAdd(Md + ((size_t)b * 49 + d) * 160 + k, acc[d]);
}

// Md f32 [b][49][160] -> Md_t bf16 [b][160][56] with 1/1179 scale
#define MD_PITCH 56
__global__ void md_transpose(const float* __restrict__ Md, bf16* __restrict__ MdT) {
    int b = blockIdx.x;
    for (int i = threadIdx.x; i < 160 * 64; i += 256) {
        int k = i >> 6, d = i & 63;
        if (d < 49)
            MdT[((size_t)b * 160 + k) * MD_PITCH + d] =
                __float2bfloat16(Md[((size_t)b * 49 + d) * 160 + k] * (1.f / 1179.f));
    }
}

// ---------------- sigmoid(M @ attW^T + attb) * conv, fused max-pool ----------------
__global__ __launch_bounds__(256) void att_sig_max(const bf16* __restrict__ Mt, int LP, int L,
                                                   int tiles, const float* __restrict__ wattT,
                                                   const float* __restrict__ attbF,
                                                   const bf16* __restrict__ conv,
                                                   float* __restrict__ pair, int off) {
    __shared__ float sM[160 * 64];
    int b = blockIdx.x / tiles;
    int p0 = (blockIdx.x % tiles) << 6;
    const bf16* mb = Mt + (size_t)b * 160 * LP;
    for (int i = threadIdx.x; i < 160 * 64; i += 256) {
        int c = i >> 6, j = i & 63;
        int p = p0 + j;
        sM[i] = (p < L) ? b2f(mb[(size_t)c * LP + p]) : 0.f;
    }
    __syncthreads();
    int li = threadIdx.x & 63;
    int sg = __builtin_amdgcn_readfirstlane(threadIdx.x >> 6);
    int o0 = blockIdx.y * 40 + sg * 10;
    float acc[10];
#pragma unroll
    for (int j = 0; j < 10; j++) acc[j] = attbF[o0 + j];
    for (int c = 0; c < 160; c++) {
        float xv = sM[(c << 6) + li];
        const float* wr = wattT + c * 160 + o0;
#pragma unroll
        for (int j = 0; j < 10; j++) acc[j] += xv * wr[j];
    }
    int p = p0 + li;
    float vmax[10];
#pragma unroll
    for (int j = 0; j < 10; j++) {
        float sig = 1.f / (1.f + __expf(-acc[j]));
        float v = 0.f;
        if (p < L) v = b2f(conv[((size_t)b * 160 + o0 + j) * L + p]) * (0.5f + sig);
        vmax[j] = v;
    }
#pragma unroll
    for (int m = 1; m < 64; m <<= 1) {
#pragma unroll
        for (int j = 0; j < 10; j++)
            vmax[j] = fmaxf(vmax[j], __shfl_xor(vmax[j], m, 64));
    }
    if (li == 0) {
#pragma unroll
        for (int j = 0; j < 10; j++)
            atomicMax((unsigned int*)(pair + b * 320 + off + o0 + j),
                      __float_as_uint(vmax[j]));
    }
}

// ---------------- MLP head ----------------
__global__ void lin_leaky(const float* __restrict__ in, const void* __restrict__ W,
                          const float* __restrict__ bias, float* __restrict__ out,
                          int IN, int OUT, const int* __restrict__ flagp) {
    int idx = blockIdx.x * 256 + threadIdx.x;
    if (idx >= NB * OUT) return;
    int b = idx / OUT, j = idx - b * OUT;
    const float4* ir4 = (const float4*)(in + (size_t)b * IN);
    float acc = bias[j];
    if (*flagp) {
        const ushort4* wr4 = (const ushort4*)((const unsigned short*)W + (size_t)j * IN);
        for (int i = 0; i < IN / 4; i++) {
            ushort4 u = wr4[i];
            float4 x = ir4[i];
            acc += x.x * u16bf(u.x) + x.y * u16bf(u.y) + x.z * u16bf(u.z) + x.w * u16bf(u.w);
        }
    } else {
        const float4* wr4 = (const float4*)((const float*)W + (size_t)j * IN);
        for (int i = 0; i < IN / 4; i++) {
            float4 w = wr4[i];
            float4 x = ir4[i];
            acc += x.x * w.x + x.y * w.y + x.z * w.z + x.w * w.w;
        }
    }
    out[idx] = acc > 0.f ? acc : 0.01f * acc;
}

__global__ void out_layer(const float* __restrict__ h, const void* __restrict__ W,
                          const float* __restrict__ biasF, void* __restrict__ out,
                          const int* __restrict__ flagp) {
    int idx = threadIdx.x;
    if (idx >= 32) return;
    int b = idx >> 1, o = idx & 1;
    float acc = biasF[o];
    const float* ir = h + b * 512;
    if (*flagp) {
        const bf16* wr = (const bf16*)W + o * 512;
        for (int i = 0; i < 512; i++) acc += ir[i] * b2f(wr[i]);
        ((bf16*)out)[idx] = __float2bfloat16(acc);
    } else {
        const float* wr = (const float*)W + o * 512;
        for (int i = 0; i < 512; i++) acc += ir[i] * wr[i];
        ((float*)out)[idx] = acc;
    }
}

extern "C" void kernel_launch(void* const* d_in, const int* in_sizes, int n_in,
                              void* d_out, int out_size, void* d_ws, size_t ws_size,
                              hipStream_t stream) {
    const int* drug_tok = (const int*)d_in[0];
    const int* prot_tok = (const int*)d_in[1];
    const void* drug_emb = d_in[2];
    const void* prot_emb = d_in[3];
    const void* dW1 = d_in[4];  const void* db1 = d_in[5];
    const void* dW2 = d_in[6];  const void* db2 = d_in[7];
    const void* dW3 = d_in[8];  const void* db3 = d_in[9];
    const void* pW1 = d_in[10]; const void* pb1 = d_in[11];
    const void* pW2 = d_in[12]; const void* pb2 = d_in[13];
    const void* pW3 = d_in[14]; const void* pb3 = d_in[15];
    const void* dattW = d_in[16]; const void* dattb = d_in[17];
    const void* pattW = d_in[18]; const void* pattb = d_in[19];
    const void* attW  = d_in[20]; const void* attb  = d_in[21];
    const void* fc1W = d_in[22]; const void* fc1b = d_in[23];
    const void* fc2W = d_in[24]; const void* fc2b = d_in[25];
    const void* fc3W = d_in[26]; const void* fc3b = d_in[27];
    const void* outW = d_in[28]; const void* outb = d_in[29];

    char* base = (char*)d_ws;
    size_t cur = 0;
    auto alloc = [&](size_t bytes) -> char* {
        char* p = base + cur;
        cur = (cur + bytes + 255) & ~(size_t)255;
        return p;
    };
    int*   flag  = (int*)alloc(256);
    float* embDF = (float*)alloc(65 * 64 * 4);
    float* embPF = (float*)alloc(26 * 64 * 4);
    float* dW1t = (float*)alloc(10240 * 4);
    float* dW2t = (float*)alloc(19200 * 4);
    float* dW3t = (float*)alloc(102400 * 4);
    float* pW1t = (float*)alloc(10240 * 4);
    float* pW2t = (float*)alloc(25600 * 4);
    float* pW3t = (float*)alloc(153600 * 4);
    float* db1f = (float*)alloc(40 * 4);
    float* db2f = (float*)alloc(80 * 4);
    float* db3f = (float*)alloc(160 * 4);
    float* pb1f = (float*)alloc(40 * 4);
    float* pb2f = (float*)alloc(80 * 4);
    float* pb3f = (float*)alloc(160 * 4);
    float* dattbF = (float*)alloc(160 * 4);
    float* pattbF = (float*)alloc(160 * 4);
    float* attbF  = (float*)alloc(160 * 4);
    float* fc1bF = (float*)alloc(1024 * 4);
    float* fc2bF = (float*)alloc(1024 * 4);
    float* fc3bF = (float*)alloc(512 * 4);
    float* outbF = (float*)alloc(2 * 4);
    float* dattT = (float*)alloc(25600 * 4);
    float* pattT = (float*)alloc(25600 * 4);
    float* wattT = (float*)alloc(25600 * 4);
    bf16* d1  = (bf16*)alloc((size_t)NB * 40 * 61 * 2);
    bf16* d2  = (bf16*)alloc((size_t)NB * 80 * 56 * 2);
    bf16* dcB = (bf16*)alloc((size_t)NB * 160 * 49 * 2);
    bf16* p1  = (bf16*)alloc((size_t)NB * 40 * 1197 * 2);
    bf16* p2  = (bf16*)alloc((size_t)NB * 80 * 1190 * 2);
    bf16* pcB = (bf16*)alloc((size_t)NB * 160 * 1179 * 2);
    float* datt  = (float*)alloc((size_t)NB * 49 * 160 * 4);
    bf16* pattB = (bf16*)alloc((size_t)NB * 1179 * 160 * 2);
    float* Md   = (float*)alloc((size_t)NB * 49 * 160 * 4);
    bf16* MdT  = (bf16*)alloc((size_t)NB * 160 * MD_PITCH * 2);
    bf16* MpT  = (bf16*)alloc((size_t)NB * 160 * MP_PITCH * 2);
    float* pair = (float*)alloc(NB * 320 * 4);
    float* h1 = (float*)alloc(NB * 1024 * 4);
    float* h2 = (float*)alloc(NB * 1024 * 4);
    float* h3 = (float*)alloc(NB * 512 * 4);

    // 1) dtype sniff
    sniff_kernel<<<1, 256, 0, stream>>>((const unsigned short*)fc2W, flag);

    // 2) parameter conversion
    CvtJob job;
    int si = 0;
    auto add = [&](const void* s, float* d, int n) { job.src[si] = s; job.dst[si] = d; job.n[si] = n; si++; };
    add(db1, db1f, 40); add(db2, db2f, 80); add(db3, db3f, 160);
    add(pb1, pb1f, 40); add(pb2, pb2f, 80); add(pb3, pb3f, 160);
    add(dattb, dattbF, 160); add(pattb, pattbF, 160); add(attb, attbF, 160);
    add(fc1b, fc1bF, 1024); add(fc2b, fc2bF, 1024); add(fc3b, fc3bF, 512);
    add(outb, outbF, 2);
    add(drug_emb, embDF, 65 * 64); add(prot_emb, embPF, 26 * 64);
    megacvt<<<dim3(17, NSEG), 256, 0, stream>>>(job, flag);
    cvt_wT<<<40, 256, 0, stream>>>(dW1, dW1t, 40, 256, flag);
    cvt_wT<<<75, 256, 0, stream>>>(dW2, dW2t, 80, 240, flag);
    cvt_wT<<<400, 256, 0, stream>>>(dW3, dW3t, 160, 640, flag);
    cvt_wT<<<40, 256, 0, stream>>>(pW1, pW1t, 40, 256, flag);
    cvt_wT<<<100, 256, 0, stream>>>(pW2, pW2t, 80, 320, flag);
    cvt_wT<<<600, 256, 0, stream>>>(pW3, pW3t, 160, 960, flag);
    cvt160t<<<dim3(100, 3), 256, 0, stream>>>(dattW, pattW, attW, dattT, pattT, wattT, flag);
    zero_init<<<(NB * 49 * 160 + 255) / 256, 256, 0, stream>>>(pair, Md);

    // 3) CNN stacks
    conv1_embed<<<dim3(NB * 1, 1), 256, 0, stream>>>(drug_tok, embDF, dW1t, db1f, d1, 64, 61, 1);
    conv1_embed<<<dim3(NB * 10, 1), 256, 0, stream>>>(prot_tok, embPF, pW1t, pb1f, p1, 1200, 1197, 10);
    conv_v3<40, 6, 10><<<dim3(NB * 1, 2), 256, 0, stream>>>(d1, dW2t, db2f, d2, 61, 56, 80, 1);
    conv_v3<40, 8, 10><<<dim3(NB * 10, 2), 256, 0, stream>>>(p1, pW2t, pb2f, p2, 1197, 1190, 80, 10);
    conv_v3<80, 8, 10><<<dim3(NB * 1, 4), 256, 0, stream>>>(d2, dW3t, db3f, dcB, 56, 49, 160, 1);
    conv_v3<80, 12, 10><<<dim3(NB * 10, 4), 256, 0, stream>>>(p2, pW3t, pb3f, pcB, 1190, 1179, 160, 10);

    // 4) attention projections
    att_proj<float><<<dim3(NB * 1, 4), 256, 0, stream>>>(dcB, dattT, dattbF, datt, 49);
    att_proj<bf16><<<dim3(NB * 19, 4), 256, 0, stream>>>(pcB, pattT, pattbF, pattB, 1179);

    // 5) pairwise relu-means
    mean_p_kernel<<<NB * 37, 192, 0, stream>>>(datt, pattB, MpT);
    mean_d_partial<<<dim3(NB, 12), 192, 0, stream>>>(datt, pattB, Md);
    md_transpose<<<NB, 256, 0, stream>>>(Md, MdT);

    // 6) fused attW-matmul + sigmoid + scale + maxpool
    att_sig_max<<<dim3(NB * 1, 4), 256, 0, stream>>>(MdT, MD_PITCH, 49, 1, wattT, attbF, dcB, pair, 0);
    att_sig_max<<<dim3(NB * 19, 4), 256, 0, stream>>>(MpT, MP_PITCH, 1179, 19, wattT, attbF, pcB, pair, 160);

    // 7) MLP head
    lin_leaky<<<(NB * 1024 + 255) / 256, 256, 0, stream>>>(pair, fc1W, fc1bF, h1, 320, 1024, flag);
    lin_leaky<<<(NB * 1024 + 255) / 256, 256, 0, stream>>>(h1, fc2W, fc2bF, h2, 1024, 1024, flag);
    lin_leaky<<<(NB * 512 + 255) / 256, 256, 0, stream>>>(h2, fc3W, fc3bF, h3, 1024, 512, flag);
    out_layer<<<1, 64, 0, stream>>>(h3, outW, outbF, d_out, flag);
}

// Round 6
// 741.556 us; speedup vs baseline: 1.2339x; 1.2339x over previous
//
#include <hip/hip_runtime.h>
#include <hip/hip_bf16.h>

typedef __hip_bfloat16 bf16;

#define NB 16

// drug conv chain:  L 64 ->61(K4,C40) ->56(K6,C80) ->49(K8,C160)
// prot conv chain:  L 1200 ->1197(K4,C40) ->1190(K8,C80) ->1179(K12,C160)

__device__ __forceinline__ float b2f(bf16 x) { return __bfloat162float(x); }
__device__ __forceinline__ float u16bf(unsigned short u) {
    return __uint_as_float(((unsigned)u) << 16);
}
__device__ __forceinline__ unsigned short f2bu(float v) {
    union { bf16 h; unsigned short u; } cv;
    cv.h = __float2bfloat16(v);
    return cv.u;
}

// ---------------- dtype sniffer (R4-proven) ----------------
__global__ void sniff_kernel(const unsigned short* __restrict__ w, int* __restrict__ flag) {
    __shared__ int cnt;
    if (threadIdx.x == 0) cnt = 0;
    __syncthreads();
    int hits = 0;
    for (int s = 0; s < 4; s++) {
        unsigned short u = w[(threadIdx.x * 4 + s) * 2];
        float v = fabsf(u16bf(u));
        if (v > 1e-6f && v < 2.0f) hits++;
    }
    atomicAdd(&cnt, hits);
    __syncthreads();
    if (threadIdx.x == 0) *flag = (cnt > 512) ? 1 : 0;
}

// ---------------- conversions (R4-proven) ----------------
#define NSEG 15
struct CvtJob {
    const void* src[NSEG];
    float* dst[NSEG];
    int n[NSEG];
};

__global__ void megacvt(CvtJob job, const int* __restrict__ flagp) {
    int seg = blockIdx.y;
    int i = blockIdx.x * 256 + threadIdx.x;
    if (i >= job.n[seg]) return;
    float v = (*flagp) ? b2f(((const bf16*)job.src[seg])[i])
                       : ((const float*)job.src[seg])[i];
    job.dst[seg][i] = v;
}

// conv weights [Cout][CIN][K] -> f32 [ci*K+k][Cout]
__global__ void cvt_wT(const void* __restrict__ src, float* __restrict__ dst,
                       int Cout, int CK, const int* __restrict__ flagp) {
    int i = blockIdx.x * 256 + threadIdx.x;
    if (i >= Cout * CK) return;
    int co = i / CK, r = i - co * CK;
    float v = (*flagp) ? b2f(((const bf16*)src)[i]) : ((const float*)src)[i];
    dst[r * Cout + co] = v;
}

// [160,160] (o,c) -> f32 transposed [c*160+o], three matrices
__global__ void cvt160t(const void* s0, const void* s1, const void* s2,
                        float* d0, float* d1, float* d2, const int* __restrict__ flagp) {
    int i = blockIdx.x * 256 + threadIdx.x;
    if (i >= 25600) return;
    const void* s = blockIdx.y == 0 ? s0 : (blockIdx.y == 1 ? s1 : s2);
    float* d = blockIdx.y == 0 ? d0 : (blockIdx.y == 1 ? d1 : d2);
    int o = i / 160, c = i % 160;
    float v = (*flagp) ? b2f(((const bf16*)s)[i]) : ((const float*)s)[i];
    d[c * 160 + o] = v;
}

__global__ void zero_init(float* __restrict__ pair, float* __restrict__ Md) {
    int i = blockIdx.x * 256 + threadIdx.x;
    if (i < NB * 320) pair[i] = 0.f;
    if (i < NB * 49 * 160) Md[i] = 0.f;
}

// ---------------- conv v4: Ltile=64, register-blocked, low LDS ----------------
template <int CIN, int K, int CPT>
__global__ __launch_bounds__(256) void conv_v4(const bf16* __restrict__ x,
                                               const float* __restrict__ wT,
                                               const float* __restrict__ bias,
                                               bf16* __restrict__ y,
                                               int Lin, int Lout, int Cout, int tilesL) {
    const int TLX = 64 + K - 1;
    __shared__ float xs[CIN * TLX];
    int b = blockIdx.x / tilesL;
    int l0 = (blockIdx.x % tilesL) << 6;
    const bf16* xb = x + (size_t)b * CIN * Lin;
    for (int i = threadIdx.x; i < CIN * TLX; i += 256) {
        int ci = i / TLX, j = i - ci * TLX;
        int l = l0 + j;
        xs[i] = (l < Lin) ? b2f(xb[ci * Lin + l]) : 0.f;
    }
    __syncthreads();
    int li = threadIdx.x & 63;
    int cg = __builtin_amdgcn_readfirstlane(threadIdx.x >> 6);
    int co0 = (blockIdx.y * 4 + cg) * CPT;
    float acc[CPT];
#pragma unroll
    for (int c = 0; c < CPT; c++) acc[c] = bias[co0 + c];
    for (int ci = 0; ci < CIN; ci++) {
        float xa[K];
        const float* xr = xs + ci * TLX + li;
#pragma unroll
        for (int t = 0; t < K; t++) xa[t] = xr[t];
        const float* wr = wT + (size_t)(ci * K) * Cout + co0;
#pragma unroll
        for (int k = 0; k < K; k++) {
#pragma unroll
            for (int c = 0; c < CPT; c++) acc[c] += xa[k] * wr[k * Cout + c];
        }
    }
    int l = l0 + li;
    if (l < Lout) {
#pragma unroll
        for (int c = 0; c < CPT; c++)
            y[((size_t)b * Cout + co0 + c) * Lout + l] = __float2bfloat16(fmaxf(acc[c], 0.f));
    }
}

// ---------------- conv1 (embedding-fused), drug+prot in one dispatch ----------------
__global__ __launch_bounds__(256) void conv1_both(const int* __restrict__ dtok,
                                                  const int* __restrict__ ptok,
                                                  const float* __restrict__ embD,
                                                  const float* __restrict__ embP,
                                                  const float* __restrict__ dW1t,
                                                  const float* __restrict__ pW1t,
                                                  const float* __restrict__ db1f,
                                                  const float* __restrict__ pb1f,
                                                  bf16* __restrict__ d1,
                                                  bf16* __restrict__ p1) {
    const int K = 4, CIN = 64, TLX = 67, CPT = 10, Cout = 40;
    __shared__ float xs[CIN * TLX];
    __shared__ int stok[TLX];
    bool isD = blockIdx.x < 16;
    int b, l0, Lin, Lout;
    const int* tok; const float* embF; const float* wT; const float* bias; bf16* y;
    if (isD) {
        b = blockIdx.x; l0 = 0; Lin = 64; Lout = 61;
        tok = dtok; embF = embD; wT = dW1t; bias = db1f; y = d1;
    } else {
        int bx = blockIdx.x - 16;
        b = bx / 19; l0 = (bx % 19) << 6; Lin = 1200; Lout = 1197;
        tok = ptok; embF = embP; wT = pW1t; bias = pb1f; y = p1;
    }
    if (threadIdx.x < TLX) {
        int l = l0 + threadIdx.x;
        stok[threadIdx.x] = (l < Lin) ? tok[b * Lin + l] : -1;
    }
    __syncthreads();
    for (int i = threadIdx.x; i < CIN * TLX; i += 256) {
        int ci = i / TLX, j = i - ci * TLX;
        int t = stok[j];
        xs[i] = (t >= 0) ? embF[t * 64 + ci] : 0.f;
    }
    __syncthreads();
    int li = threadIdx.x & 63;
    int cg = __builtin_amdgcn_readfirstlane(threadIdx.x >> 6);
    int co0 = cg * CPT;
    float acc[CPT];
#pragma unroll
    for (int c = 0; c < CPT; c++) acc[c] = bias[co0 + c];
    for (int ci = 0; ci < CIN; ci++) {
        float xa[K];
        const float* xr = xs + ci * TLX + li;
#pragma unroll
        for (int t = 0; t < K; t++) xa[t] = xr[t];
        const float* wr = wT + (size_t)(ci * K) * Cout + co0;
#pragma unroll
        for (int k = 0; k < K; k++) {
#pragma unroll
            for (int c = 0; c < CPT; c++) acc[c] += xa[k] * wr[k * Cout + c];
        }
    }
    int l = l0 + li;
    if (l < Lout) {
#pragma unroll
        for (int c = 0; c < CPT; c++)
            y[((size_t)b * Cout + co0 + c) * Lout + l] = __float2bfloat16(fmaxf(acc[c], 0.f));
    }
}

// ---------------- attention projections, drug+prot in one dispatch ----------------
__global__ __launch_bounds__(256) void att_proj_both(const bf16* __restrict__ dcB,
                                                     const bf16* __restrict__ pcB,
                                                     const float* __restrict__ dattT,
                                                     const float* __restrict__ pattT,
                                                     const float* __restrict__ dattbF,
                                                     const float* __restrict__ pattbF,
                                                     float* __restrict__ datt,
                                                     bf16* __restrict__ pattB) {
    __shared__ float xs[160 * 64];
    bool isD = blockIdx.x < 16;
    int b, l0, L;
    const bf16* xsrc; const float* wt; const float* bias;
    if (isD) {
        b = blockIdx.x; l0 = 0; L = 49;
        xsrc = dcB; wt = dattT; bias = dattbF;
    } else {
        int bx = blockIdx.x - 16;
        b = bx / 19; l0 = (bx % 19) << 6; L = 1179;
        xsrc = pcB; wt = pattT; bias = pattbF;
    }
    const bf16* xb = xsrc + (size_t)b * 160 * L;
    for (int i = threadIdx.x; i < 160 * 64; i += 256) {
        int c = i >> 6, j = i & 63;
        int l = l0 + j;
        xs[i] = (l < L) ? b2f(xb[c * L + l]) : 0.f;
    }
    __syncthreads();
    int li = threadIdx.x & 63;
    int og = __builtin_amdgcn_readfirstlane(threadIdx.x >> 6);
    int o0 = blockIdx.y * 40 + og * 10;
    float acc[10];
#pragma unroll
    for (int j = 0; j < 10; j++) acc[j] = bias[o0 + j];
    for (int c = 0; c < 160; c++) {
        float xv = xs[(c << 6) + li];
        const float* wr = wt + c * 160 + o0;
#pragma unroll
        for (int j = 0; j < 10; j++) acc[j] += xv * wr[j];
    }
    int l = l0 + li;
    if (l < L) {
        if (isD) {
            float* yr = datt + ((size_t)b * 49 + l) * 160 + o0;
#pragma unroll
            for (int j = 0; j < 10; j++) yr[j] = acc[j];
        } else {
            bf16* yr = pattB + ((size_t)b * 1179 + l) * 160 + o0;
#pragma unroll
            for (int j = 0; j < 10; j++) yr[j] = __float2bfloat16(acc[j]);
        }
    }
}

// ---------------- mean over d (->MpT) and mean over p (->Md) in one dispatch ----------------
#define MP_PITCH 1184
__global__ __launch_bounds__(192) void mean_both(const float* __restrict__ datt,
                                                 const bf16* __restrict__ patt,
                                                 bf16* __restrict__ MpT,
                                                 float* __restrict__ Md) {
    int k = threadIdx.x;
    if (k >= 160) return;
    if (blockIdx.x < 592) {
        int b = blockIdx.x / 37;
        int p0 = (blockIdx.x % 37) * 32;
        float dv[49];
#pragma unroll
        for (int d = 0; d < 49; d++) dv[d] = datt[((size_t)b * 49 + d) * 160 + k];
        float s[32];
#pragma unroll
        for (int pi = 0; pi < 32; pi++) {
            int p = p0 + pi;
            float acc = 0.f;
            if (p < 1179) {
                float pv = b2f(patt[((size_t)b * 1179 + p) * 160 + k]);
#pragma unroll
                for (int d = 0; d < 49; d++) acc += fmaxf(dv[d] + pv, 0.f);
            }
            s[pi] = acc * (1.f / 49.f);
        }
        unsigned short* row = (unsigned short*)MpT + ((size_t)b * 160 + k) * MP_PITCH + p0;
#pragma unroll
        for (int g = 0; g < 8; g++) {
            ushort4 u;
            u.x = f2bu(s[g * 4 + 0]); u.y = f2bu(s[g * 4 + 1]);
            u.z = f2bu(s[g * 4 + 2]); u.w = f2bu(s[g * 4 + 3]);
            *(ushort4*)(row + g * 4) = u;
        }
    } else {
        int ps = blockIdx.x - 592;
        int b = ps / 24, ch = ps - b * 24;
        int p0 = ch * 50, p1 = min(p0 + 50, 1179);
        float dv[49], acc[49];
#pragma unroll
        for (int d = 0; d < 49; d++) {
            dv[d] = datt[((size_t)b * 49 + d) * 160 + k];
            acc[d] = 0.f;
        }
        for (int p = p0; p < p1; p++) {
            float pv = b2f(patt[((size_t)b * 1179 + p) * 160 + k]);
#pragma unroll
            for (int d = 0; d < 49; d++) acc[d] += fmaxf(dv[d] + pv, 0.f);
        }
#pragma unroll
        for (int d = 0; d < 49; d++)
            atomicAdd(Md + ((size_t)b * 49 + d) * 160 + k, acc[d]);
    }
}

// ---------------- sigmoid(M @ attW^T + attb) * conv + maxpool, drug+prot ----------------
__global__ __launch_bounds__(256) void att_sig_both(const float* __restrict__ Md,
                                                    const bf16* __restrict__ MpT,
                                                    const float* __restrict__ wattT,
                                                    const float* __restrict__ attbF,
                                                    const bf16* __restrict__ dcB,
                                                    const bf16* __restrict__ pcB,
                                                    float* __restrict__ pair) {
    __shared__ float sM[160 * 64];
    bool isD = blockIdx.x < 16;
    int b, p0, L, off;
    const bf16* conv;
    if (isD) {
        b = blockIdx.x; p0 = 0; L = 49; off = 0; conv = dcB;
        for (int i = threadIdx.x; i < 160 * 64; i += 256) {
            int c = i >> 6, j = i & 63;
            sM[i] = (j < 49) ? Md[((size_t)b * 49 + j) * 160 + c] * (1.f / 1179.f) : 0.f;
        }
    } else {
        int bx = blockIdx.x - 16;
        b = bx / 19; p0 = (bx % 19) << 6; L = 1179; off = 160; conv = pcB;
        const bf16* mb = MpT + (size_t)b * 160 * MP_PITCH;
        for (int i = threadIdx.x; i < 160 * 64; i += 256) {
            int c = i >> 6, j = i & 63;
            int p = p0 + j;
            sM[i] = (p < L) ? b2f(mb[(size_t)c * MP_PITCH + p]) : 0.f;
        }
    }
    __syncthreads();
    int li = threadIdx.x & 63;
    int sg = __builtin_amdgcn_readfirstlane(threadIdx.x >> 6);
    int o0 = blockIdx.y * 40 + sg * 10;
    float acc[10];
#pragma unroll
    for (int j = 0; j < 10; j++) acc[j] = attbF[o0 + j];
    for (int c = 0; c < 160; c++) {
        float xv = sM[(c << 6) + li];
        const float* wr = wattT + c * 160 + o0;
#pragma unroll
        for (int j = 0; j < 10; j++) acc[j] += xv * wr[j];
    }
    int p = p0 + li;
    float vmax[10];
#pragma unroll
    for (int j = 0; j < 10; j++) {
        float sig = 1.f / (1.f + __expf(-acc[j]));
        float v = 0.f;
        if (p < L) v = b2f(conv[((size_t)b * 160 + o0 + j) * L + p]) * (0.5f + sig);
        vmax[j] = v;
    }
#pragma unroll
    for (int m = 1; m < 64; m <<= 1) {
#pragma unroll
        for (int j = 0; j < 10; j++)
            vmax[j] = fmaxf(vmax[j], __shfl_xor(vmax[j], m, 64));
    }
    if (li == 0) {
#pragma unroll
        for (int j = 0; j < 10; j++)
            atomicMax((unsigned int*)(pair + b * 320 + off + o0 + j),
                      __float_as_uint(vmax[j]));
    }
}

// ---------------- MLP head (R4-proven, flag from memory) ----------------
__global__ void lin_leaky(const float* __restrict__ in, const void* __restrict__ W,
                          const float* __restrict__ bias, float* __restrict__ out,
                          int IN, int OUT, const int* __restrict__ flagp) {
    int idx = blockIdx.x * 256 + threadIdx.x;
    if (idx >= NB * OUT) return;
    int b = idx / OUT, j = idx - b * OUT;
    const float4* ir4 = (const float4*)(in + (size_t)b * IN);
    float acc = bias[j];
    if (*flagp) {
        const ushort4* wr4 = (const ushort4*)((const unsigned short*)W + (size_t)j * IN);
        for (int i = 0; i < IN / 4; i++) {
            ushort4 u = wr4[i];
            float4 x = ir4[i];
            acc += x.x * u16bf(u.x) + x.y * u16bf(u.y) + x.z * u16bf(u.z) + x.w * u16bf(u.w);
        }
    } else {
        const float4* wr4 = (const float4*)((const float*)W + (size_t)j * IN);
        for (int i = 0; i < IN / 4; i++) {
            float4 w = wr4[i];
            float4 x = ir4[i];
            acc += x.x * w.x + x.y * w.y + x.z * w.z + x.w * w.w;
        }
    }
    out[idx] = acc > 0.f ? acc : 0.01f * acc;
}

__global__ void out_layer(const float* __restrict__ h, const void* __restrict__ W,
                          const float* __restrict__ biasF, void* __restrict__ out,
                          const int* __restrict__ flagp) {
    int idx = threadIdx.x;
    if (idx >= 32) return;
    int b = idx >> 1, o = idx & 1;
    float acc = biasF[o];
    const float* ir = h + b * 512;
    if (*flagp) {
        const bf16* wr = (const bf16*)W + o * 512;
        for (int i = 0; i < 512; i++) acc += ir[i] * b2f(wr[i]);
        ((bf16*)out)[idx] = __float2bfloat16(acc);
    } else {
        const float* wr = (const float*)W + o * 512;
        for (int i = 0; i < 512; i++) acc += ir[i] * wr[i];
        ((float*)out)[idx] = acc;
    }
}

extern "C" void kernel_launch(void* const* d_in, const int* in_sizes, int n_in,
                              void* d_out, int out_size, void* d_ws, size_t ws_size,
                              hipStream_t stream) {
    const int* drug_tok = (const int*)d_in[0];
    const int* prot_tok = (const int*)d_in[1];
    const void* drug_emb = d_in[2];
    const void* prot_emb = d_in[3];
    const void* dW1 = d_in[4];  const void* db1 = d_in[5];
    const void* dW2 = d_in[6];  const void* db2 = d_in[7];
    const void* dW3 = d_in[8];  const void* db3 = d_in[9];
    const void* pW1 = d_in[10]; const void* pb1 = d_in[11];
    const void* pW2 = d_in[12]; const void* pb2 = d_in[13];
    const void* pW3 = d_in[14]; const void* pb3 = d_in[15];
    const void* dattW = d_in[16]; const void* dattb = d_in[17];
    const void* pattW = d_in[18]; const void* pattb = d_in[19];
    const void* attW  = d_in[20]; const void* attb  = d_in[21];
    const void* fc1W = d_in[22]; const void* fc1b = d_in[23];
    const void* fc2W = d_in[24]; const void* fc2b = d_in[25];
    const void* fc3W = d_in[26]; const void* fc3b = d_in[27];
    const void* outW = d_in[28]; const void* outb = d_in[29];

    char* base = (char*)d_ws;
    size_t cur = 0;
    auto alloc = [&](size_t bytes) -> char* {
        char* p = base + cur;
        cur = (cur + bytes + 255) & ~(size_t)255;
        return p;
    };
    int*   flag  = (int*)alloc(256);
    float* embDF = (float*)alloc(65 * 64 * 4);
    float* embPF = (float*)alloc(26 * 64 * 4);
    float* dW1t = (float*)alloc(10240 * 4);
    float* dW2t = (float*)alloc(19200 * 4);
    float* dW3t = (float*)alloc(102400 * 4);
    float* pW1t = (float*)alloc(10240 * 4);
    float* pW2t = (float*)alloc(25600 * 4);
    float* pW3t = (float*)alloc(153600 * 4);
    float* db1f = (float*)alloc(40 * 4);
    float* db2f = (float*)alloc(80 * 4);
    float* db3f = (float*)alloc(160 * 4);
    float* pb1f = (float*)alloc(40 * 4);
    float* pb2f = (float*)alloc(80 * 4);
    float* pb3f = (float*)alloc(160 * 4);
    float* dattbF = (float*)alloc(160 * 4);
    float* pattbF = (float*)alloc(160 * 4);
    float* attbF  = (float*)alloc(160 * 4);
    float* fc1bF = (float*)alloc(1024 * 4);
    float* fc2bF = (float*)alloc(1024 * 4);
    float* fc3bF = (float*)alloc(512 * 4);
    float* outbF = (float*)alloc(2 * 4);
    float* dattT = (float*)alloc(25600 * 4);
    float* pattT = (float*)alloc(25600 * 4);
    float* wattT = (float*)alloc(25600 * 4);
    bf16* d1  = (bf16*)alloc((size_t)NB * 40 * 61 * 2);
    bf16* d2  = (bf16*)alloc((size_t)NB * 80 * 56 * 2);
    bf16* dcB = (bf16*)alloc((size_t)NB * 160 * 49 * 2);
    bf16* p1  = (bf16*)alloc((size_t)NB * 40 * 1197 * 2);
    bf16* p2  = (bf16*)alloc((size_t)NB * 80 * 1190 * 2);
    bf16* pcB = (bf16*)alloc((size_t)NB * 160 * 1179 * 2);
    float* datt  = (float*)alloc((size_t)NB * 49 * 160 * 4);
    bf16* pattB = (bf16*)alloc((size_t)NB * 1179 * 160 * 2);
    float* Md   = (float*)alloc((size_t)NB * 49 * 160 * 4);
    bf16* MpT  = (bf16*)alloc((size_t)NB * 160 * MP_PITCH * 2);
    float* pair = (float*)alloc(NB * 320 * 4);
    float* h1 = (float*)alloc(NB * 1024 * 4);
    float* h2 = (float*)alloc(NB * 1024 * 4);
    float* h3 = (float*)alloc(NB * 512 * 4);

    // 1) dtype sniff (R4-proven)
    sniff_kernel<<<1, 256, 0, stream>>>((const unsigned short*)fc2W, flag);

    // 2) parameter conversion (R4-proven path)
    CvtJob job;
    int si = 0;
    auto add = [&](const void* s, float* d, int n) { job.src[si] = s; job.dst[si] = d; job.n[si] = n; si++; };
    add(db1, db1f, 40); add(db2, db2f, 80); add(db3, db3f, 160);
    add(pb1, pb1f, 40); add(pb2, pb2f, 80); add(pb3, pb3f, 160);
    add(dattb, dattbF, 160); add(pattb, pattbF, 160); add(attb, attbF, 160);
    add(fc1b, fc1bF, 1024); add(fc2b, fc2bF, 1024); add(fc3b, fc3bF, 512);
    add(outb, outbF, 2);
    add(drug_emb, embDF, 65 * 64); add(prot_emb, embPF, 26 * 64);
    megacvt<<<dim3(17, NSEG), 256, 0, stream>>>(job, flag);
    cvt_wT<<<40, 256, 0, stream>>>(dW1, dW1t, 40, 256, flag);
    cvt_wT<<<75, 256, 0, stream>>>(dW2, dW2t, 80, 240, flag);
    cvt_wT<<<400, 256, 0, stream>>>(dW3, dW3t, 160, 640, flag);
    cvt_wT<<<40, 256, 0, stream>>>(pW1, pW1t, 40, 256, flag);
    cvt_wT<<<100, 256, 0, stream>>>(pW2, pW2t, 80, 320, flag);
    cvt_wT<<<600, 256, 0, stream>>>(pW3, pW3t, 160, 960, flag);
    cvt160t<<<dim3(100, 3), 256, 0, stream>>>(dattW, pattW, attW, dattT, pattT, wattT, flag);
    zero_init<<<(NB * 49 * 160 + 255) / 256, 256, 0, stream>>>(pair, Md);

    // 3) CNN stacks (merged conv1; Ltile=64 occupancy fix)
    conv1_both<<<16 + 16 * 19, 256, 0, stream>>>(drug_tok, prot_tok, embDF, embPF,
                                                 dW1t, pW1t, db1f, pb1f, d1, p1);
    conv_v4<40, 6, 10><<<dim3(16, 2), 256, 0, stream>>>(d1, dW2t, db2f, d2, 61, 56, 80, 1);
    conv_v4<40, 8, 10><<<dim3(16 * 19, 2), 256, 0, stream>>>(p1, pW2t, pb2f, p2, 1197, 1190, 80, 19);
    conv_v4<80, 8, 10><<<dim3(16, 4), 256, 0, stream>>>(d2, dW3t, db3f, dcB, 56, 49, 160, 1);
    conv_v4<80, 12, 10><<<dim3(16 * 19, 4), 256, 0, stream>>>(p2, pW3t, pb3f, pcB, 1190, 1179, 160, 19);

    // 4) attention projections (one dispatch)
    att_proj_both<<<dim3(16 + 304, 4), 256, 0, stream>>>(dcB, pcB, dattT, pattT,
                                                         dattbF, pattbF, datt, pattB);

    // 5) pairwise relu-means (one dispatch)
    mean_both<<<592 + 384, 192, 0, stream>>>(datt, pattB, MpT, Md);

    // 6) fused attW-matmul + sigmoid + scale + maxpool (one dispatch)
    att_sig_both<<<dim3(16 + 304, 4), 256, 0, stream>>>(Md, MpT, wattT, attbF, dcB, pcB, pair);

    // 7) MLP head
    lin_leaky<<<(NB * 1024 + 255) / 256, 256, 0, stream>>>(pair, fc1W, fc1bF, h1, 320, 1024, flag);
    lin_leaky<<<(NB * 1024 + 255) / 256, 256, 0, stream>>>(h1, fc2W, fc2bF, h2, 1024, 1024, flag);
    lin_leaky<<<(NB * 512 + 255) / 256, 256, 0, stream>>>(h2, fc3W, fc3bF, h3, 1024, 512, flag);
    out_layer<<<1, 64, 0, stream>>>(h3, outW, outbF, d_out, flag);
}

// Round 7
// 487.660 us; speedup vs baseline: 1.8763x; 1.5206x over previous
//
#include <hip/hip_runtime.h>
#include <hip/hip_bf16.h>

typedef __hip_bfloat16 bf16;
typedef __attribute__((ext_vector_type(8))) short short8;
typedef __attribute__((ext_vector_type(4))) float floatx4;

#define NB 16

// drug conv chain:  L 64 ->61(K4,C40) ->56(K6,C80) ->49(K8,C160)
// prot conv chain:  L 1200 ->1197(K4,C40) ->1190(K8,C80) ->1179(K12,C160)

__device__ __forceinline__ float b2f(bf16 x) { return __bfloat162float(x); }
__device__ __forceinline__ float u16bf(unsigned short u) {
    return __uint_as_float(((unsigned)u) << 16);
}
__device__ __forceinline__ unsigned short f2bu(float v) {
    union { bf16 h; unsigned short u; } cv;
    cv.h = __float2bfloat16(v);
    return cv.u;
}

// ---------------- dtype sniffer (R4-proven) ----------------
__global__ void sniff_kernel(const unsigned short* __restrict__ w, int* __restrict__ flag) {
    __shared__ int cnt;
    if (threadIdx.x == 0) cnt = 0;
    __syncthreads();
    int hits = 0;
    for (int s = 0; s < 4; s++) {
        unsigned short u = w[(threadIdx.x * 4 + s) * 2];
        float v = fabsf(u16bf(u));
        if (v > 1e-6f && v < 2.0f) hits++;
    }
    atomicAdd(&cnt, hits);
    __syncthreads();
    if (threadIdx.x == 0) *flag = (cnt > 512) ? 1 : 0;
}

// ---------------- conversions (R4-proven) ----------------
#define NSEG 15
struct CvtJob {
    const void* src[NSEG];
    float* dst[NSEG];
    int n[NSEG];
};

__global__ void megacvt(CvtJob job, const int* __restrict__ flagp) {
    int seg = blockIdx.y;
    int i = blockIdx.x * 256 + threadIdx.x;
    if (i >= job.n[seg]) return;
    float v = (*flagp) ? b2f(((const bf16*)job.src[seg])[i])
                       : ((const float*)job.src[seg])[i];
    job.dst[seg][i] = v;
}

// conv weights [Cout][CIN][K] -> f32 [ci*K+k][Cout]  (conv1 only now)
__global__ void cvt_wT(const void* __restrict__ src, float* __restrict__ dst,
                       int Cout, int CK, const int* __restrict__ flagp) {
    int i = blockIdx.x * 256 + threadIdx.x;
    if (i >= Cout * CK) return;
    int co = i / CK, r = i - co * CK;
    float v = (*flagp) ? b2f(((const bf16*)src)[i]) : ((const float*)src)[i];
    dst[r * Cout + co] = v;
}

// conv weights [Cout][CIN][K] -> bf16 MFMA pack [k][coP][CIP] (zero-padded)
__global__ void pack_wmfma(const void* __restrict__ src, bf16* __restrict__ dst,
                           int Cout, int CIN, int K, int coP, int CIP,
                           const int* __restrict__ flagp) {
    int i = blockIdx.x * 256 + threadIdx.x;
    int total = K * coP * CIP;
    if (i >= total) return;
    int ci = i % CIP;
    int t = i / CIP;
    int co = t % coP;
    int k = t / coP;
    float v = 0.f;
    if (co < Cout && ci < CIN) {
        int s = (co * CIN + ci) * K + k;
        v = (*flagp) ? b2f(((const bf16*)src)[s]) : ((const float*)src)[s];
    }
    dst[i] = __float2bfloat16(v);
}

// [160,160] (o,c) -> f32 transposed [c*160+o], three matrices
__global__ void cvt160t(const void* s0, const void* s1, const void* s2,
                        float* d0, float* d1, float* d2, const int* __restrict__ flagp) {
    int i = blockIdx.x * 256 + threadIdx.x;
    if (i >= 25600) return;
    const void* s = blockIdx.y == 0 ? s0 : (blockIdx.y == 1 ? s1 : s2);
    float* d = blockIdx.y == 0 ? d0 : (blockIdx.y == 1 ? d1 : d2);
    int o = i / 160, c = i % 160;
    float v = (*flagp) ? b2f(((const bf16*)s)[i]) : ((const float*)s)[i];
    d[c * 160 + o] = v;
}

__global__ void zero_init(float* __restrict__ pair, float* __restrict__ Md) {
    int i = blockIdx.x * 256 + threadIdx.x;
    if (i < NB * 320) pair[i] = 0.f;
    if (i < NB * 49 * 160) Md[i] = 0.f;
}

// ---------------- conv via MFMA implicit GEMM ----------------
// C[co][l] = sum_k sum_ci Wk[k][co][ci] * X[ci][l+k]
// Wp: bf16 [k][coP][CIP]; X staged transposed in LDS xT[l][ci] (pitch CIP+8).
// Per wave: one 16-co tile (ct = blockIdx.y*4 + wave), 4 pos sub-tiles (64 pos).
// A-frag = 16B global load; B-frag = one ds_read_b128. mfma_f32_16x16x32_bf16.
// Layouts [measured learn_hip m89/m118]: A[m=lane&15][k=quad*8+j],
// B[k=quad*8+j][n=lane&15], D: row(co)=quad*4+reg, col(pos)=lane&15.
template <int K, int CIN, int CHUNKS>
__global__ __launch_bounds__(256) void conv_mfma(const bf16* __restrict__ x,
                                                 const bf16* __restrict__ Wp,
                                                 const float* __restrict__ bias,
                                                 bf16* __restrict__ y,
                                                 int Lin, int Lout, int Cout,
                                                 int coP, int tilesL) {
    const int CIP = CHUNKS * 32;
    const int PCI = CIP + 8;           // LDS pitch: conflict-optimal for b128
    const int TLX = 64 + K - 1;
    __shared__ __align__(16) unsigned short xT[TLX * PCI];
    int b = blockIdx.x / tilesL;
    int l0 = (blockIdx.x % tilesL) << 6;
    const unsigned short* xb = (const unsigned short*)x + (size_t)b * CIN * Lin;
    for (int i = threadIdx.x; i < TLX * CIP; i += 256) {
        int ci = i / TLX, l = i - ci * TLX;
        unsigned short v = 0;
        int gl = l0 + l;
        if (ci < CIN && gl < Lin) v = xb[ci * Lin + gl];
        xT[l * PCI + ci] = v;
    }
    __syncthreads();
    int lane = threadIdx.x & 63;
    int w = threadIdx.x >> 6;
    int ct = blockIdx.y * 4 + w;       // 16-wide co tile index (< coP/16 always)
    int n = lane & 15, quad = lane >> 4;
    floatx4 acc[4];
#pragma unroll
    for (int i = 0; i < 4; i++) acc[i] = (floatx4){0.f, 0.f, 0.f, 0.f};
    const unsigned short* wbase = (const unsigned short*)Wp;
#pragma unroll
    for (int k = 0; k < K; k++) {
#pragma unroll
        for (int ch = 0; ch < CHUNKS; ch++) {
            short8 a = *(const short8*)(wbase +
                        ((size_t)(k * coP + ct * 16 + n)) * CIP + ch * 32 + quad * 8);
#pragma unroll
            for (int nt = 0; nt < 4; nt++) {
                short8 bb = *(const short8*)(xT + (nt * 16 + n + k) * PCI + ch * 32 + quad * 8);
                acc[nt] = __builtin_amdgcn_mfma_f32_16x16x32_bf16(a, bb, acc[nt], 0, 0, 0);
            }
        }
    }
    int m0 = quad * 4;
#pragma unroll
    for (int nt = 0; nt < 4; nt++) {
        int l = l0 + nt * 16 + n;
        if (l >= Lout) continue;
#pragma unroll
        for (int r = 0; r < 4; r++) {
            int co = ct * 16 + m0 + r;
            if (co < Cout)
                y[((size_t)b * Cout + co) * Lout + l] =
                    __float2bfloat16(fmaxf(acc[nt][r] + bias[co], 0.f));
        }
    }
}

// ---------------- conv1 (embedding-fused), drug+prot in one dispatch (R6-proven) ----------------
__global__ __launch_bounds__(256) void conv1_both(const int* __restrict__ dtok,
                                                  const int* __restrict__ ptok,
                                                  const float* __restrict__ embD,
                                                  const float* __restrict__ embP,
                                                  const float* __restrict__ dW1t,
                                                  const float* __restrict__ pW1t,
                                                  const float* __restrict__ db1f,
                                                  const float* __restrict__ pb1f,
                                                  bf16* __restrict__ d1,
                                                  bf16* __restrict__ p1) {
    const int K = 4, CIN = 64, TLX = 67, CPT = 10, Cout = 40;
    __shared__ float xs[CIN * TLX];
    __shared__ int stok[TLX];
    bool isD = blockIdx.x < 16;
    int b, l0, Lin, Lout;
    const int* tok; const float* embF; const float* wT; const float* bias; bf16* y;
    if (isD) {
        b = blockIdx.x; l0 = 0; Lin = 64; Lout = 61;
        tok = dtok; embF = embD; wT = dW1t; bias = db1f; y = d1;
    } else {
        int bx = blockIdx.x - 16;
        b = bx / 19; l0 = (bx % 19) << 6; Lin = 1200; Lout = 1197;
        tok = ptok; embF = embP; wT = pW1t; bias = pb1f; y = p1;
    }
    if (threadIdx.x < TLX) {
        int l = l0 + threadIdx.x;
        stok[threadIdx.x] = (l < Lin) ? tok[b * Lin + l] : -1;
    }
    __syncthreads();
    for (int i = threadIdx.x; i < CIN * TLX; i += 256) {
        int ci = i / TLX, j = i - ci * TLX;
        int t = stok[j];
        xs[i] = (t >= 0) ? embF[t * 64 + ci] : 0.f;
    }
    __syncthreads();
    int li = threadIdx.x & 63;
    int cg = __builtin_amdgcn_readfirstlane(threadIdx.x >> 6);
    int co0 = cg * CPT;
    float acc[CPT];
#pragma unroll
    for (int c = 0; c < CPT; c++) acc[c] = bias[co0 + c];
    for (int ci = 0; ci < CIN; ci++) {
        float xa[K];
        const float* xr = xs + ci * TLX + li;
#pragma unroll
        for (int t = 0; t < K; t++) xa[t] = xr[t];
        const float* wr = wT + (size_t)(ci * K) * Cout + co0;
#pragma unroll
        for (int k = 0; k < K; k++) {
#pragma unroll
            for (int c = 0; c < CPT; c++) acc[c] += xa[k] * wr[k * Cout + c];
        }
    }
    int l = l0 + li;
    if (l < Lout) {
#pragma unroll
        for (int c = 0; c < CPT; c++)
            y[((size_t)b * Cout + co0 + c) * Lout + l] = __float2bfloat16(fmaxf(acc[c], 0.f));
    }
}

// ---------------- attention projections, drug+prot in one dispatch (R6-proven) ----------------
__global__ __launch_bounds__(256) void att_proj_both(const bf16* __restrict__ dcB,
                                                     const bf16* __restrict__ pcB,
                                                     const float* __restrict__ dattT,
                                                     const float* __restrict__ pattT,
                                                     const float* __restrict__ dattbF,
                                                     const float* __restrict__ pattbF,
                                                     float* __restrict__ datt,
                                                     bf16* __restrict__ pattB) {
    __shared__ float xs[160 * 64];
    bool isD = blockIdx.x < 16;
    int b, l0, L;
    const bf16* xsrc; const float* wt; const float* bias;
    if (isD) {
        b = blockIdx.x; l0 = 0; L = 49;
        xsrc = dcB; wt = dattT; bias = dattbF;
    } else {
        int bx = blockIdx.x - 16;
        b = bx / 19; l0 = (bx % 19) << 6; L = 1179;
        xsrc = pcB; wt = pattT; bias = pattbF;
    }
    const bf16* xb = xsrc + (size_t)b * 160 * L;
    for (int i = threadIdx.x; i < 160 * 64; i += 256) {
        int c = i >> 6, j = i & 63;
        int l = l0 + j;
        xs[i] = (l < L) ? b2f(xb[c * L + l]) : 0.f;
    }
    __syncthreads();
    int li = threadIdx.x & 63;
    int og = __builtin_amdgcn_readfirstlane(threadIdx.x >> 6);
    int o0 = blockIdx.y * 40 + og * 10;
    float acc[10];
#pragma unroll
    for (int j = 0; j < 10; j++) acc[j] = bias[o0 + j];
    for (int c = 0; c < 160; c++) {
        float xv = xs[(c << 6) + li];
        const float* wr = wt + c * 160 + o0;
#pragma unroll
        for (int j = 0; j < 10; j++) acc[j] += xv * wr[j];
    }
    int l = l0 + li;
    if (l < L) {
        if (isD) {
            float* yr = datt + ((size_t)b * 49 + l) * 160 + o0;
#pragma unroll
            for (int j = 0; j < 10; j++) yr[j] = acc[j];
        } else {
            bf16* yr = pattB + ((size_t)b * 1179 + l) * 160 + o0;
#pragma unroll
            for (int j = 0; j < 10; j++) yr[j] = __float2bfloat16(acc[j]);
        }
    }
}

// ---------------- mean over d (->MpT) and mean over p (->Md) in one dispatch (R6-proven) ----------------
#define MP_PITCH 1184
__global__ __launch_bounds__(192) void mean_both(const float* __restrict__ datt,
                                                 const bf16* __restrict__ patt,
                                                 bf16* __restrict__ MpT,
                                                 float* __restrict__ Md) {
    int k = threadIdx.x;
    if (k >= 160) return;
    if (blockIdx.x < 592) {
        int b = blockIdx.x / 37;
        int p0 = (blockIdx.x % 37) * 32;
        float dv[49];
#pragma unroll
        for (int d = 0; d < 49; d++) dv[d] = datt[((size_t)b * 49 + d) * 160 + k];
        float s[32];
#pragma unroll
        for (int pi = 0; pi < 32; pi++) {
            int p = p0 + pi;
            float acc = 0.f;
            if (p < 1179) {
                float pv = b2f(patt[((size_t)b * 1179 + p) * 160 + k]);
#pragma unroll
                for (int d = 0; d < 49; d++) acc += fmaxf(dv[d] + pv, 0.f);
            }
            s[pi] = acc * (1.f / 49.f);
        }
        unsigned short* row = (unsigned short*)MpT + ((size_t)b * 160 + k) * MP_PITCH + p0;
#pragma unroll
        for (int g = 0; g < 8; g++) {
            ushort4 u;
            u.x = f2bu(s[g * 4 + 0]); u.y = f2bu(s[g * 4 + 1]);
            u.z = f2bu(s[g * 4 + 2]); u.w = f2bu(s[g * 4 + 3]);
            *(ushort4*)(row + g * 4) = u;
        }
    } else {
        int ps = blockIdx.x - 592;
        int b = ps / 24, ch = ps - b * 24;
        int p0 = ch * 50, p1 = min(p0 + 50, 1179);
        float dv[49], acc[49];
#pragma unroll
        for (int d = 0; d < 49; d++) {
            dv[d] = datt[((size_t)b * 49 + d) * 160 + k];
            acc[d] = 0.f;
        }
        for (int p = p0; p < p1; p++) {
            float pv = b2f(patt[((size_t)b * 1179 + p) * 160 + k]);
#pragma unroll
            for (int d = 0; d < 49; d++) acc[d] += fmaxf(dv[d] + pv, 0.f);
        }
#pragma unroll
        for (int d = 0; d < 49; d++)
            atomicAdd(Md + ((size_t)b * 49 + d) * 160 + k, acc[d]);
    }
}

// ---------------- sigmoid(M @ attW^T + attb) * conv + maxpool, drug+prot (R6-proven) ----------------
__global__ __launch_bounds__(256) void att_sig_both(const float* __restrict__ Md,
                                                    const bf16* __restrict__ MpT,
                                                    const float* __restrict__ wattT,
                                                    const float* __restrict__ attbF,
                                                    const bf16* __restrict__ dcB,
                                                    const bf16* __restrict__ pcB,
                                                    float* __restrict__ pair) {
    __shared__ float sM[160 * 64];
    bool isD = blockIdx.x < 16;
    int b, p0, L, off;
    const bf16* conv;
    if (isD) {
        b = blockIdx.x; p0 = 0; L = 49; off = 0; conv = dcB;
        for (int i = threadIdx.x; i < 160 * 64; i += 256) {
            int c = i >> 6, j = i & 63;
            sM[i] = (j < 49) ? Md[((size_t)b * 49 + j) * 160 + c] * (1.f / 1179.f) : 0.f;
        }
    } else {
        int bx = blockIdx.x - 16;
        b = bx / 19; p0 = (bx % 19) << 6; L = 1179; off = 160; conv = pcB;
        const bf16* mb = MpT + (size_t)b * 160 * MP_PITCH;
        for (int i = threadIdx.x; i < 160 * 64; i += 256) {
            int c = i >> 6, j = i & 63;
            int p = p0 + j;
            sM[i] = (p < L) ? b2f(mb[(size_t)c * MP_PITCH + p]) : 0.f;
        }
    }
    __syncthreads();
    int li = threadIdx.x & 63;
    int sg = __builtin_amdgcn_readfirstlane(threadIdx.x >> 6);
    int o0 = blockIdx.y * 40 + sg * 10;
    float acc[10];
#pragma unroll
    for (int j = 0; j < 10; j++) acc[j] = attbF[o0 + j];
    for (int c = 0; c < 160; c++) {
        float xv = sM[(c << 6) + li];
        const float* wr = wattT + c * 160 + o0;
#pragma unroll
        for (int j = 0; j < 10; j++) acc[j] += xv * wr[j];
    }
    int p = p0 + li;
    float vmax[10];
#pragma unroll
    for (int j = 0; j < 10; j++) {
        float sig = 1.f / (1.f + __expf(-acc[j]));
        float v = 0.f;
        if (p < L) v = b2f(conv[((size_t)b * 160 + o0 + j) * L + p]) * (0.5f + sig);
        vmax[j] = v;
    }
#pragma unroll
    for (int m = 1; m < 64; m <<= 1) {
#pragma unroll
        for (int j = 0; j < 10; j++)
            vmax[j] = fmaxf(vmax[j], __shfl_xor(vmax[j], m, 64));
    }
    if (li == 0) {
#pragma unroll
        for (int j = 0; j < 10; j++)
            atomicMax((unsigned int*)(pair + b * 320 + off + o0 + j),
                      __float_as_uint(vmax[j]));
    }
}

// ---------------- MLP head (R4-proven) ----------------
__global__ void lin_leaky(const float* __restrict__ in, const void* __restrict__ W,
                          const float* __restrict__ bias, float* __restrict__ out,
                          int IN, int OUT, const int* __restrict__ flagp) {
    int idx = blockIdx.x * 256 + threadIdx.x;
    if (idx >= NB * OUT) return;
    int b = idx / OUT, j = idx - b * OUT;
    const float4* ir4 = (const float4*)(in + (size_t)b * IN);
    float acc = bias[j];
    if (*flagp) {
        const ushort4* wr4 = (const ushort4*)((const unsigned short*)W + (size_t)j * IN);
        for (int i = 0; i < IN / 4; i++) {
            ushort4 u = wr4[i];
            float4 x = ir4[i];
            acc += x.x * u16bf(u.x) + x.y * u16bf(u.y) + x.z * u16bf(u.z) + x.w * u16bf(u.w);
        }
    } else {
        const float4* wr4 = (const float4*)((const float*)W + (size_t)j * IN);
        for (int i = 0; i < IN / 4; i++) {
            float4 w = wr4[i];
            float4 x = ir4[i];
            acc += x.x * w.x + x.y * w.y + x.z * w.z + x.w * w.w;
        }
    }
    out[idx] = acc > 0.f ? acc : 0.01f * acc;
}

__global__ void out_layer(const float* __restrict__ h, const void* __restrict__ W,
                          const float* __restrict__ biasF, void* __restrict__ out,
                          const int* __restrict__ flagp) {
    int idx = threadIdx.x;
    if (idx >= 32) return;
    int b = idx >> 1, o = idx & 1;
    float acc = biasF[o];
    const float* ir = h + b * 512;
    if (*flagp) {
        const bf16* wr = (const bf16*)W + o * 512;
        for (int i = 0; i < 512; i++) acc += ir[i] * b2f(wr[i]);
        ((bf16*)out)[idx] = __float2bfloat16(acc);
    } else {
        const float* wr = (const float*)W + o * 512;
        for (int i = 0; i < 512; i++) acc += ir[i] * wr[i];
        ((float*)out)[idx] = acc;
    }
}

extern "C" void kernel_launch(void* const* d_in, const int* in_sizes, int n_in,
                              void* d_out, int out_size, void* d_ws, size_t ws_size,
                              hipStream_t stream) {
    const int* drug_tok = (const int*)d_in[0];
    const int* prot_tok = (const int*)d_in[1];
    const void* drug_emb = d_in[2];
    const void* prot_emb = d_in[3];
    const void* dW1 = d_in[4];  const void* db1 = d_in[5];
    const void* dW2 = d_in[6];  const void* db2 = d_in[7];
    const void* dW3 = d_in[8];  const void* db3 = d_in[9];
    const void* pW1 = d_in[10]; const void* pb1 = d_in[11];
    const void* pW2 = d_in[12]; const void* pb2 = d_in[13];
    const void* pW3 = d_in[14]; const void* pb3 = d_in[15];
    const void* dattW = d_in[16]; const void* dattb = d_in[17];
    const void* pattW = d_in[18]; const void* pattb = d_in[19];
    const void* attW  = d_in[20]; const void* attb  = d_in[21];
    const void* fc1W = d_in[22]; const void* fc1b = d_in[23];
    const void* fc2W = d_in[24]; const void* fc2b = d_in[25];
    const void* fc3W = d_in[26]; const void* fc3b = d_in[27];
    const void* outW = d_in[28]; const void* outb = d_in[29];

    char* base = (char*)d_ws;
    size_t cur = 0;
    auto alloc = [&](size_t bytes) -> char* {
        char* p = base + cur;
        cur = (cur + bytes + 255) & ~(size_t)255;
        return p;
    };
    int*   flag  = (int*)alloc(256);
    float* embDF = (float*)alloc(65 * 64 * 4);
    float* embPF = (float*)alloc(26 * 64 * 4);
    float* dW1t = (float*)alloc(10240 * 4);
    float* pW1t = (float*)alloc(10240 * 4);
    bf16* dW2p = (bf16*)alloc((size_t)6 * 128 * 64 * 2);
    bf16* dW3p = (bf16*)alloc((size_t)8 * 192 * 96 * 2);
    bf16* pW2p = (bf16*)alloc((size_t)8 * 128 * 64 * 2);
    bf16* pW3p = (bf16*)alloc((size_t)12 * 192 * 96 * 2);
    float* db1f = (float*)alloc(40 * 4);
    float* db2f = (float*)alloc(80 * 4);
    float* db3f = (float*)alloc(160 * 4);
    float* pb1f = (float*)alloc(40 * 4);
    float* pb2f = (float*)alloc(80 * 4);
    float* pb3f = (float*)alloc(160 * 4);
    float* dattbF = (float*)alloc(160 * 4);
    float* pattbF = (float*)alloc(160 * 4);
    float* attbF  = (float*)alloc(160 * 4);
    float* fc1bF = (float*)alloc(1024 * 4);
    float* fc2bF = (float*)alloc(1024 * 4);
    float* fc3bF = (float*)alloc(512 * 4);
    float* outbF = (float*)alloc(2 * 4);
    float* dattT = (float*)alloc(25600 * 4);
    float* pattT = (float*)alloc(25600 * 4);
    float* wattT = (float*)alloc(25600 * 4);
    bf16* d1  = (bf16*)alloc((size_t)NB * 40 * 61 * 2);
    bf16* d2  = (bf16*)alloc((size_t)NB * 80 * 56 * 2);
    bf16* dcB = (bf16*)alloc((size_t)NB * 160 * 49 * 2);
    bf16* p1  = (bf16*)alloc((size_t)NB * 40 * 1197 * 2);
    bf16* p2  = (bf16*)alloc((size_t)NB * 80 * 1190 * 2);
    bf16* pcB = (bf16*)alloc((size_t)NB * 160 * 1179 * 2);
    float* datt  = (float*)alloc((size_t)NB * 49 * 160 * 4);
    bf16* pattB = (bf16*)alloc((size_t)NB * 1179 * 160 * 2);
    float* Md   = (float*)alloc((size_t)NB * 49 * 160 * 4);
    bf16* MpT  = (bf16*)alloc((size_t)NB * 160 * MP_PITCH * 2);
    float* pair = (float*)alloc(NB * 320 * 4);
    float* h1 = (float*)alloc(NB * 1024 * 4);
    float* h2 = (float*)alloc(NB * 1024 * 4);
    float* h3 = (float*)alloc(NB * 512 * 4);

    // 1) dtype sniff
    sniff_kernel<<<1, 256, 0, stream>>>((const unsigned short*)fc2W, flag);

    // 2) parameter conversion
    CvtJob job;
    int si = 0;
    auto add = [&](const void* s, float* d, int n) { job.src[si] = s; job.dst[si] = d; job.n[si] = n; si++; };
    add(db1, db1f, 40); add(db2, db2f, 80); add(db3, db3f, 160);
    add(pb1, pb1f, 40); add(pb2, pb2f, 80); add(pb3, pb3f, 160);
    add(dattb, dattbF, 160); add(pattb, pattbF, 160); add(attb, attbF, 160);
    add(fc1b, fc1bF, 1024); add(fc2b, fc2bF, 1024); add(fc3b, fc3bF, 512);
    add(outb, outbF, 2);
    add(drug_emb, embDF, 65 * 64); add(prot_emb, embPF, 26 * 64);
    megacvt<<<dim3(17, NSEG), 256, 0, stream>>>(job, flag);
    cvt_wT<<<40, 256, 0, stream>>>(dW1, dW1t, 40, 256, flag);
    cvt_wT<<<40, 256, 0, stream>>>(pW1, pW1t, 40, 256, flag);
    pack_wmfma<<<192, 256, 0, stream>>>(dW2, dW2p, 80, 40, 6, 128, 64, flag);
    pack_wmfma<<<576, 256, 0, stream>>>(dW3, dW3p, 160, 80, 8, 192, 96, flag);
    pack_wmfma<<<256, 256, 0, stream>>>(pW2, pW2p, 80, 40, 8, 128, 64, flag);
    pack_wmfma<<<864, 256, 0, stream>>>(pW3, pW3p, 160, 80, 12, 192, 96, flag);
    cvt160t<<<dim3(100, 3), 256, 0, stream>>>(dattW, pattW, attW, dattT, pattT, wattT, flag);
    zero_init<<<(NB * 49 * 160 + 255) / 256, 256, 0, stream>>>(pair, Md);

    // 3) CNN stacks: conv1 VALU (R6-proven), conv2/3 MFMA implicit GEMM
    conv1_both<<<16 + 16 * 19, 256, 0, stream>>>(drug_tok, prot_tok, embDF, embPF,
                                                 dW1t, pW1t, db1f, pb1f, d1, p1);
    conv_mfma<6, 40, 2><<<dim3(16, 2), 256, 0, stream>>>(d1, dW2p, db2f, d2, 61, 56, 80, 128, 1);
    conv_mfma<8, 40, 2><<<dim3(16 * 19, 2), 256, 0, stream>>>(p1, pW2p, pb2f, p2, 1197, 1190, 80, 128, 19);
    conv_mfma<8, 80, 3><<<dim3(16, 3), 256, 0, stream>>>(d2, dW3p, db3f, dcB, 56, 49, 160, 192, 1);
    conv_mfma<12, 80, 3><<<dim3(16 * 19, 3), 256, 0, stream>>>(p2, pW3p, pb3f, pcB, 1190, 1179, 160, 192, 19);

    // 4) attention projections (one dispatch)
    att_proj_both<<<dim3(16 + 304, 4), 256, 0, stream>>>(dcB, pcB, dattT, pattT,
                                                         dattbF, pattbF, datt, pattB);

    // 5) pairwise relu-means (one dispatch)
    mean_both<<<592 + 384, 192, 0, stream>>>(datt, pattB, MpT, Md);

    // 6) fused attW-matmul + sigmoid + scale + maxpool (one dispatch)
    att_sig_both<<<dim3(16 + 304, 4), 256, 0, stream>>>(Md, MpT, wattT, attbF, dcB, pcB, pair);

    // 7) MLP head
    lin_leaky<<<(NB * 1024 + 255) / 256, 256, 0, stream>>>(pair, fc1W, fc1bF, h1, 320, 1024, flag);
    lin_leaky<<<(NB * 1024 + 255) / 256, 256, 0, stream>>>(h1, fc2W, fc2bF, h2, 1024, 1024, flag);
    lin_leaky<<<(NB * 512 + 255) / 256, 256, 0, stream>>>(h2, fc3W, fc3bF, h3, 1024, 512, flag);
    out_layer<<<1, 64, 0, stream>>>(h3, outW, outbF, d_out, flag);
}

// Round 8
// 430.337 us; speedup vs baseline: 2.1263x; 1.1332x over previous
//
#include <hip/hip_runtime.h>
#include <hip/hip_bf16.h>

typedef __hip_bfloat16 bf16;
typedef __attribute__((ext_vector_type(8))) short short8;
typedef __attribute__((ext_vector_type(4))) float floatx4;

#define NB 16

// drug conv chain:  L 64 ->61(K4,C40) ->56(K6,C80) ->49(K8,C160)
// prot conv chain:  L 1200 ->1197(K4,C40) ->1190(K8,C80) ->1179(K12,C160)

__device__ __forceinline__ float b2f(bf16 x) { return __bfloat162float(x); }
__device__ __forceinline__ float u16bf(unsigned short u) {
    return __uint_as_float(((unsigned)u) << 16);
}
__device__ __forceinline__ unsigned short f2bu(float v) {
    union { bf16 h; unsigned short u; } cv;
    cv.h = __float2bfloat16(v);
    return cv.u;
}

// ---------------- dtype sniffer (R4-proven) ----------------
__global__ void sniff_kernel(const unsigned short* __restrict__ w, int* __restrict__ flag) {
    __shared__ int cnt;
    if (threadIdx.x == 0) cnt = 0;
    __syncthreads();
    int hits = 0;
    for (int s = 0; s < 4; s++) {
        unsigned short u = w[(threadIdx.x * 4 + s) * 2];
        float v = fabsf(u16bf(u));
        if (v > 1e-6f && v < 2.0f) hits++;
    }
    atomicAdd(&cnt, hits);
    __syncthreads();
    if (threadIdx.x == 0) *flag = (cnt > 512) ? 1 : 0;
}

// ---------------- conversions ----------------
#define NSEG 15
struct CvtJob {
    const void* src[NSEG];
    float* dst[NSEG];
    int n[NSEG];
};

__global__ void megacvt(CvtJob job, const int* __restrict__ flagp) {
    int seg = blockIdx.y;
    int i = blockIdx.x * 256 + threadIdx.x;
    if (i >= job.n[seg]) return;
    float v = (*flagp) ? b2f(((const bf16*)job.src[seg])[i])
                       : ((const float*)job.src[seg])[i];
    job.dst[seg][i] = v;
}

// conv weights [Cout][CIN][K] -> f32 [ci*K+k][Cout]  (conv1 only)
__global__ void cvt_wT(const void* __restrict__ src, float* __restrict__ dst,
                       int Cout, int CK, const int* __restrict__ flagp) {
    int i = blockIdx.x * 256 + threadIdx.x;
    if (i >= Cout * CK) return;
    int co = i / CK, r = i - co * CK;
    float v = (*flagp) ? b2f(((const bf16*)src)[i]) : ((const float*)src)[i];
    dst[r * Cout + co] = v;
}

// conv weights [Cout][CIN][K] -> bf16 MFMA pack [k][coP][CIP] (zero-padded)
__global__ void pack_wmfma(const void* __restrict__ src, bf16* __restrict__ dst,
                           int Cout, int CIN, int K, int coP, int CIP,
                           const int* __restrict__ flagp) {
    int i = blockIdx.x * 256 + threadIdx.x;
    int total = K * coP * CIP;
    if (i >= total) return;
    int ci = i % CIP;
    int t = i / CIP;
    int co = t % coP;
    int k = t / coP;
    float v = 0.f;
    if (co < Cout && ci < CIN) {
        int s = (co * CIN + ci) * K + k;
        v = (*flagp) ? b2f(((const bf16*)src)[s]) : ((const float*)src)[s];
    }
    dst[i] = __float2bfloat16(v);
}

// [160,160] (o,c) -> bf16 [o][c] (A-operand layout, no transpose), 3 matrices
__global__ void cvt160b(const void* s0, const void* s1, const void* s2,
                        bf16* d0, bf16* d1, bf16* d2, const int* __restrict__ flagp) {
    int i = blockIdx.x * 256 + threadIdx.x;
    if (i >= 25600) return;
    const void* s = blockIdx.y == 0 ? s0 : (blockIdx.y == 1 ? s1 : s2);
    bf16* d = blockIdx.y == 0 ? d0 : (blockIdx.y == 1 ? d1 : d2);
    float v = (*flagp) ? b2f(((const bf16*)s)[i]) : ((const float*)s)[i];
    d[i] = __float2bfloat16(v);
}

__global__ void zero_init(float* __restrict__ pair, float* __restrict__ Md) {
    int i = blockIdx.x * 256 + threadIdx.x;
    if (i < NB * 320) pair[i] = 0.f;
    if (i < NB * 49 * 160) Md[i] = 0.f;
}

// ---------------- conv via MFMA implicit GEMM (R7-proven) ----------------
template <int K, int CIN, int CHUNKS>
__global__ __launch_bounds__(256) void conv_mfma(const bf16* __restrict__ x,
                                                 const bf16* __restrict__ Wp,
                                                 const float* __restrict__ bias,
                                                 bf16* __restrict__ y,
                                                 int Lin, int Lout, int Cout,
                                                 int coP, int tilesL) {
    const int CIP = CHUNKS * 32;
    const int PCI = CIP + 8;
    const int TLX = 64 + K - 1;
    __shared__ __align__(16) unsigned short xT[TLX * PCI];
    int b = blockIdx.x / tilesL;
    int l0 = (blockIdx.x % tilesL) << 6;
    const unsigned short* xb = (const unsigned short*)x + (size_t)b * CIN * Lin;
    for (int i = threadIdx.x; i < TLX * CIP; i += 256) {
        int ci = i / TLX, l = i - ci * TLX;
        unsigned short v = 0;
        int gl = l0 + l;
        if (ci < CIN && gl < Lin) v = xb[ci * Lin + gl];
        xT[l * PCI + ci] = v;
    }
    __syncthreads();
    int lane = threadIdx.x & 63;
    int w = threadIdx.x >> 6;
    int ct = blockIdx.y * 4 + w;
    int n = lane & 15, quad = lane >> 4;
    floatx4 acc[4];
#pragma unroll
    for (int i = 0; i < 4; i++) acc[i] = (floatx4){0.f, 0.f, 0.f, 0.f};
    const unsigned short* wbase = (const unsigned short*)Wp;
#pragma unroll
    for (int k = 0; k < K; k++) {
#pragma unroll
        for (int ch = 0; ch < CHUNKS; ch++) {
            short8 a = *(const short8*)(wbase +
                        ((size_t)(k * coP + ct * 16 + n)) * CIP + ch * 32 + quad * 8);
#pragma unroll
            for (int nt = 0; nt < 4; nt++) {
                short8 bb = *(const short8*)(xT + (nt * 16 + n + k) * PCI + ch * 32 + quad * 8);
                acc[nt] = __builtin_amdgcn_mfma_f32_16x16x32_bf16(a, bb, acc[nt], 0, 0, 0);
            }
        }
    }
    int m0 = quad * 4;
#pragma unroll
    for (int nt = 0; nt < 4; nt++) {
        int l = l0 + nt * 16 + n;
        if (l >= Lout) continue;
#pragma unroll
        for (int r = 0; r < 4; r++) {
            int co = ct * 16 + m0 + r;
            if (co < Cout)
                y[((size_t)b * Cout + co) * Lout + l] =
                    __float2bfloat16(fmaxf(acc[nt][r] + bias[co], 0.f));
        }
    }
}

// ---------------- conv1 (embedding-fused), drug+prot (R6-proven) ----------------
__global__ __launch_bounds__(256) void conv1_both(const int* __restrict__ dtok,
                                                  const int* __restrict__ ptok,
                                                  const float* __restrict__ embD,
                                                  const float* __restrict__ embP,
                                                  const float* __restrict__ dW1t,
                                                  const float* __restrict__ pW1t,
                                                  const float* __restrict__ db1f,
                                                  const float* __restrict__ pb1f,
                                                  bf16* __restrict__ d1,
                                                  bf16* __restrict__ p1) {
    const int K = 4, CIN = 64, TLX = 67, CPT = 10, Cout = 40;
    __shared__ float xs[CIN * TLX];
    __shared__ int stok[TLX];
    bool isD = blockIdx.x < 16;
    int b, l0, Lin, Lout;
    const int* tok; const float* embF; const float* wT; const float* bias; bf16* y;
    if (isD) {
        b = blockIdx.x; l0 = 0; Lin = 64; Lout = 61;
        tok = dtok; embF = embD; wT = dW1t; bias = db1f; y = d1;
    } else {
        int bx = blockIdx.x - 16;
        b = bx / 19; l0 = (bx % 19) << 6; Lin = 1200; Lout = 1197;
        tok = ptok; embF = embP; wT = pW1t; bias = pb1f; y = p1;
    }
    if (threadIdx.x < TLX) {
        int l = l0 + threadIdx.x;
        stok[threadIdx.x] = (l < Lin) ? tok[b * Lin + l] : -1;
    }
    __syncthreads();
    for (int i = threadIdx.x; i < CIN * TLX; i += 256) {
        int ci = i / TLX, j = i - ci * TLX;
        int t = stok[j];
        xs[i] = (t >= 0) ? embF[t * 64 + ci] : 0.f;
    }
    __syncthreads();
    int li = threadIdx.x & 63;
    int cg = __builtin_amdgcn_readfirstlane(threadIdx.x >> 6);
    int co0 = cg * CPT;
    float acc[CPT];
#pragma unroll
    for (int c = 0; c < CPT; c++) acc[c] = bias[co0 + c];
    for (int ci = 0; ci < CIN; ci++) {
        float xa[K];
        const float* xr = xs + ci * TLX + li;
#pragma unroll
        for (int t = 0; t < K; t++) xa[t] = xr[t];
        const float* wr = wT + (size_t)(ci * K) * Cout + co0;
#pragma unroll
        for (int k = 0; k < K; k++) {
#pragma unroll
            for (int c = 0; c < CPT; c++) acc[c] += xa[k] * wr[k * Cout + c];
        }
    }
    int l = l0 + li;
    if (l < Lout) {
#pragma unroll
        for (int c = 0; c < CPT; c++)
            y[((size_t)b * Cout + co0 + c) * Lout + l] = __float2bfloat16(fmaxf(acc[c], 0.f));
    }
}

// ---------------- attention projection via MFMA, drug+prot ----------------
// y[l][o] = sum_c x[c][l] * W[o][c] + bias[o]. A = W (already [o][c]); B = xT LDS.
// grid (320, 3): tile t = blockIdx.y*4 + wave, t<10.
__global__ __launch_bounds__(256) void att_proj_mfma(const bf16* __restrict__ dcB,
                                                     const bf16* __restrict__ pcB,
                                                     const bf16* __restrict__ dWB,
                                                     const bf16* __restrict__ pWB,
                                                     const float* __restrict__ dbF,
                                                     const float* __restrict__ pbF,
                                                     float* __restrict__ datt,
                                                     bf16* __restrict__ pattB) {
    const int PCI = 168;
    __shared__ __align__(16) unsigned short xT[64 * PCI];
    bool isD = blockIdx.x < 16;
    int b, l0, L;
    const unsigned short* xsrc; const unsigned short* W; const float* bias;
    if (isD) {
        b = blockIdx.x; l0 = 0; L = 49;
        xsrc = (const unsigned short*)dcB; W = (const unsigned short*)dWB; bias = dbF;
    } else {
        int bx = blockIdx.x - 16;
        b = bx / 19; l0 = (bx % 19) << 6; L = 1179;
        xsrc = (const unsigned short*)pcB; W = (const unsigned short*)pWB; bias = pbF;
    }
    const unsigned short* xb = xsrc + (size_t)b * 160 * L;
    for (int i = threadIdx.x; i < 160 * 64; i += 256) {
        int c = i >> 6, j = i & 63;
        int l = l0 + j;
        xT[j * PCI + c] = (l < L) ? xb[(size_t)c * L + l] : (unsigned short)0;
    }
    __syncthreads();
    int lane = threadIdx.x & 63;
    int w = threadIdx.x >> 6;
    int t = blockIdx.y * 4 + w;
    int n = lane & 15, quad = lane >> 4;
    if (t >= 10) return;
    floatx4 acc[4];
#pragma unroll
    for (int i = 0; i < 4; i++) acc[i] = (floatx4){0.f, 0.f, 0.f, 0.f};
#pragma unroll
    for (int ch = 0; ch < 5; ch++) {
        short8 a = *(const short8*)(W + ((size_t)(t * 16 + n)) * 160 + ch * 32 + quad * 8);
#pragma unroll
        for (int nt = 0; nt < 4; nt++) {
            short8 bb = *(const short8*)(xT + (nt * 16 + n) * PCI + ch * 32 + quad * 8);
            acc[nt] = __builtin_amdgcn_mfma_f32_16x16x32_bf16(a, bb, acc[nt], 0, 0, 0);
        }
    }
    int m0 = quad * 4;
    int o0 = t * 16 + m0;
#pragma unroll
    for (int nt = 0; nt < 4; nt++) {
        int l = l0 + nt * 16 + n;
        if (l >= L) continue;
        if (isD) {
            float4 v;
            v.x = acc[nt][0] + bias[o0 + 0];
            v.y = acc[nt][1] + bias[o0 + 1];
            v.z = acc[nt][2] + bias[o0 + 2];
            v.w = acc[nt][3] + bias[o0 + 3];
            *(float4*)(datt + ((size_t)b * 49 + l) * 160 + o0) = v;
        } else {
            ushort4 u;
            u.x = f2bu(acc[nt][0] + bias[o0 + 0]);
            u.y = f2bu(acc[nt][1] + bias[o0 + 1]);
            u.z = f2bu(acc[nt][2] + bias[o0 + 2]);
            u.w = f2bu(acc[nt][3] + bias[o0 + 3]);
            *(ushort4*)((unsigned short*)pattB + ((size_t)b * 1179 + l) * 160 + o0) = u;
        }
    }
}

// ---------------- means: MpW [p][k] (d-outer ILP fix) + Md partials ----------------
__global__ __launch_bounds__(192) void mean_both(const float* __restrict__ datt,
                                                 const bf16* __restrict__ patt,
                                                 bf16* __restrict__ MpW,
                                                 float* __restrict__ Md) {
    int k = threadIdx.x;
    if (k >= 160) return;
    if (blockIdx.x < 592) {
        int b = blockIdx.x / 37;
        int p0 = (blockIdx.x % 37) * 32;
        float dv[49];
#pragma unroll
        for (int d = 0; d < 49; d++) dv[d] = datt[((size_t)b * 49 + d) * 160 + k];
#pragma unroll
        for (int half = 0; half < 2; half++) {
            float pv[16], s[16];
#pragma unroll
            for (int pi = 0; pi < 16; pi++) {
                int p = p0 + half * 16 + pi;
                pv[pi] = (p < 1179) ? b2f(patt[((size_t)b * 1179 + p) * 160 + k]) : 0.f;
                s[pi] = 0.f;
            }
            for (int d = 0; d < 49; d++) {
                float dvv = dv[d];
#pragma unroll
                for (int pi = 0; pi < 16; pi++) s[pi] += fmaxf(dvv + pv[pi], 0.f);
            }
#pragma unroll
            for (int pi = 0; pi < 16; pi++) {
                int p = p0 + half * 16 + pi;
                MpW[((size_t)b * 1184 + p) * 160 + k] = __float2bfloat16(s[pi] * (1.f / 49.f));
            }
        }
    } else {
        int ps = blockIdx.x - 592;
        int b = ps / 24, ch = ps - b * 24;
        int p0 = ch * 50, p1 = min(p0 + 50, 1179);
        float dv[49], acc[49];
#pragma unroll
        for (int d = 0; d < 49; d++) {
            dv[d] = datt[((size_t)b * 49 + d) * 160 + k];
            acc[d] = 0.f;
        }
        for (int p = p0; p < p1; p++) {
            float pv = b2f(patt[((size_t)b * 1179 + p) * 160 + k]);
#pragma unroll
            for (int d = 0; d < 49; d++) acc[d] += fmaxf(dv[d] + pv, 0.f);
        }
#pragma unroll
        for (int d = 0; d < 49; d++)
            atomicAdd(Md + ((size_t)b * 49 + d) * 160 + k, acc[d]);
    }
}

// ---------------- att_sig via MFMA + fused sigmoid/scale/maxpool ----------------
// grid (320, 3): tile t = blockIdx.y*4 + wave, t<10.
__global__ __launch_bounds__(256) void att_sig_mfma(const float* __restrict__ Md,
                                                    const bf16* __restrict__ MpW,
                                                    const bf16* __restrict__ wattB,
                                                    const float* __restrict__ attbF,
                                                    const bf16* __restrict__ dcB,
                                                    const bf16* __restrict__ pcB,
                                                    float* __restrict__ pair) {
    const int PCI = 168;
    __shared__ __align__(16) unsigned short sM[64 * PCI];
    bool isD = blockIdx.x < 16;
    int b, p0, L, off;
    const unsigned short* conv;
    if (isD) {
        b = blockIdx.x; p0 = 0; L = 49; off = 0; conv = (const unsigned short*)dcB;
        for (int i = threadIdx.x; i < 160 * 64; i += 256) {
            int r = i / 160, k = i - r * 160;
            float v = (r < 49) ? Md[((size_t)b * 49 + r) * 160 + k] * (1.f / 1179.f) : 0.f;
            sM[r * PCI + k] = f2bu(v);
        }
    } else {
        int bx = blockIdx.x - 16;
        b = bx / 19; p0 = (bx % 19) << 6; L = 1179; off = 160;
        conv = (const unsigned short*)pcB;
        const unsigned short* mb = (const unsigned short*)MpW + (size_t)b * 1184 * 160;
        for (int i = threadIdx.x; i < 160 * 64; i += 256) {
            int r = i / 160, k = i - r * 160;
            int p = p0 + r;
            sM[r * PCI + k] = (p < 1184) ? mb[(size_t)p * 160 + k] : (unsigned short)0;
        }
    }
    __syncthreads();
    int lane = threadIdx.x & 63;
    int w = threadIdx.x >> 6;
    int t = blockIdx.y * 4 + w;
    int n = lane & 15, quad = lane >> 4;
    if (t >= 10) return;
    floatx4 acc[4];
#pragma unroll
    for (int i = 0; i < 4; i++) acc[i] = (floatx4){0.f, 0.f, 0.f, 0.f};
    const unsigned short* W = (const unsigned short*)wattB;
#pragma unroll
    for (int ch = 0; ch < 5; ch++) {
        short8 a = *(const short8*)(W + ((size_t)(t * 16 + n)) * 160 + ch * 32 + quad * 8);
#pragma unroll
        for (int nt = 0; nt < 4; nt++) {
            short8 bb = *(const short8*)(sM + (nt * 16 + n) * PCI + ch * 32 + quad * 8);
            acc[nt] = __builtin_amdgcn_mfma_f32_16x16x32_bf16(a, bb, acc[nt], 0, 0, 0);
        }
    }
    int m0 = quad * 4;
    float vmax[4] = {0.f, 0.f, 0.f, 0.f};
#pragma unroll
    for (int nt = 0; nt < 4; nt++) {
        int p = p0 + nt * 16 + n;
#pragma unroll
        for (int r = 0; r < 4; r++) {
            int o = t * 16 + m0 + r;
            float sig = 1.f / (1.f + __expf(-(acc[nt][r] + attbF[o])));
            float v = 0.f;
            if (p < L) v = u16bf(conv[((size_t)b * 160 + o) * L + p]) * (0.5f + sig);
            vmax[r] = fmaxf(vmax[r], v);
        }
    }
#pragma unroll
    for (int m = 1; m < 16; m <<= 1) {
#pragma unroll
        for (int r = 0; r < 4; r++)
            vmax[r] = fmaxf(vmax[r], __shfl_xor(vmax[r], m, 64));
    }
    if (n == 0) {
#pragma unroll
        for (int r = 0; r < 4; r++)
            atomicMax((unsigned int*)(pair + b * 320 + off + t * 16 + m0 + r),
                      __float_as_uint(vmax[r]));
    }
}

// ---------------- MLP head (R4-proven) ----------------
__global__ void lin_leaky(const float* __restrict__ in, const void* __restrict__ W,
                          const float* __restrict__ bias, float* __restrict__ out,
                          int IN, int OUT, const int* __restrict__ flagp) {
    int idx = blockIdx.x * 256 + threadIdx.x;
    if (idx >= NB * OUT) return;
    int b = idx / OUT, j = idx - b * OUT;
    const float4* ir4 = (const float4*)(in + (size_t)b * IN);
    float acc = bias[j];
    if (*flagp) {
        const ushort4* wr4 = (const ushort4*)((const unsigned short*)W + (size_t)j * IN);
        for (int i = 0; i < IN / 4; i++) {
            ushort4 u = wr4[i];
            float4 x = ir4[i];
            acc += x.x * u16bf(u.x) + x.y * u16bf(u.y) + x.z * u16bf(u.z) + x.w * u16bf(u.w);
        }
    } else {
        const float4* wr4 = (const float4*)((const float*)W + (size_t)j * IN);
        for (int i = 0; i < IN / 4; i++) {
            float4 w = wr4[i];
            float4 x = ir4[i];
            acc += x.x * w.x + x.y * w.y + x.z * w.z + x.w * w.w;
        }
    }
    out[idx] = acc > 0.f ? acc : 0.01f * acc;
}

__global__ void out_layer(const float* __restrict__ h, const void* __restrict__ W,
                          const float* __restrict__ biasF, void* __restrict__ out,
                          const int* __restrict__ flagp) {
    int idx = threadIdx.x;
    if (idx >= 32) return;
    int b = idx >> 1, o = idx & 1;
    float acc = biasF[o];
    const float* ir = h + b * 512;
    if (*flagp) {
        const bf16* wr = (const bf16*)W + o * 512;
        for (int i = 0; i < 512; i++) acc += ir[i] * b2f(wr[i]);
        ((bf16*)out)[idx] = __float2bfloat16(acc);
    } else {
        const float* wr = (const float*)W + o * 512;
        for (int i = 0; i < 512; i++) acc += ir[i] * wr[i];
        ((float*)out)[idx] = acc;
    }
}

extern "C" void kernel_launch(void* const* d_in, const int* in_sizes, int n_in,
                              void* d_out, int out_size, void* d_ws, size_t ws_size,
                              hipStream_t stream) {
    const int* drug_tok = (const int*)d_in[0];
    const int* prot_tok = (const int*)d_in[1];
    const void* drug_emb = d_in[2];
    const void* prot_emb = d_in[3];
    const void* dW1 = d_in[4];  const void* db1 = d_in[5];
    const void* dW2 = d_in[6];  const void* db2 = d_in[7];
    const void* dW3 = d_in[8];  const void* db3 = d_in[9];
    const void* pW1 = d_in[10]; const void* pb1 = d_in[11];
    const void* pW2 = d_in[12]; const void* pb2 = d_in[13];
    const void* pW3 = d_in[14]; const void* pb3 = d_in[15];
    const void* dattW = d_in[16]; const void* dattb = d_in[17];
    const void* pattW = d_in[18]; const void* pattb = d_in[19];
    const void* attW  = d_in[20]; const void* attb  = d_in[21];
    const void* fc1W = d_in[22]; const void* fc1b = d_in[23];
    const void* fc2W = d_in[24]; const void* fc2b = d_in[25];
    const void* fc3W = d_in[26]; const void* fc3b = d_in[27];
    const void* outW = d_in[28]; const void* outb = d_in[29];

    char* base = (char*)d_ws;
    size_t cur = 0;
    auto alloc = [&](size_t bytes) -> char* {
        char* p = base + cur;
        cur = (cur + bytes + 255) & ~(size_t)255;
        return p;
    };
    int*   flag  = (int*)alloc(256);
    float* embDF = (float*)alloc(65 * 64 * 4);
    float* embPF = (float*)alloc(26 * 64 * 4);
    float* dW1t = (float*)alloc(10240 * 4);
    float* pW1t = (float*)alloc(10240 * 4);
    bf16* dW2p = (bf16*)alloc((size_t)6 * 128 * 64 * 2);
    bf16* dW3p = (bf16*)alloc((size_t)8 * 192 * 96 * 2);
    bf16* pW2p = (bf16*)alloc((size_t)8 * 128 * 64 * 2);
    bf16* pW3p = (bf16*)alloc((size_t)12 * 192 * 96 * 2);
    float* db1f = (float*)alloc(40 * 4);
    float* db2f = (float*)alloc(80 * 4);
    float* db3f = (float*)alloc(160 * 4);
    float* pb1f = (float*)alloc(40 * 4);
    float* pb2f = (float*)alloc(80 * 4);
    float* pb3f = (float*)alloc(160 * 4);
    float* dattbF = (float*)alloc(160 * 4);
    float* pattbF = (float*)alloc(160 * 4);
    float* attbF  = (float*)alloc(160 * 4);
    float* fc1bF = (float*)alloc(1024 * 4);
    float* fc2bF = (float*)alloc(1024 * 4);
    float* fc3bF = (float*)alloc(512 * 4);
    float* outbF = (float*)alloc(2 * 4);
    bf16* dattWB = (bf16*)alloc(25600 * 2);
    bf16* pattWB = (bf16*)alloc(25600 * 2);
    bf16* wattB  = (bf16*)alloc(25600 * 2);
    bf16* d1  = (bf16*)alloc((size_t)NB * 40 * 61 * 2);
    bf16* d2  = (bf16*)alloc((size_t)NB * 80 * 56 * 2);
    bf16* dcB = (bf16*)alloc((size_t)NB * 160 * 49 * 2);
    bf16* p1  = (bf16*)alloc((size_t)NB * 40 * 1197 * 2);
    bf16* p2  = (bf16*)alloc((size_t)NB * 80 * 1190 * 2);
    bf16* pcB = (bf16*)alloc((size_t)NB * 160 * 1179 * 2);
    float* datt  = (float*)alloc((size_t)NB * 49 * 160 * 4);
    bf16* pattB = (bf16*)alloc((size_t)NB * 1179 * 160 * 2);
    float* Md   = (float*)alloc((size_t)NB * 49 * 160 * 4);
    bf16* MpW  = (bf16*)alloc((size_t)NB * 1184 * 160 * 2);
    float* pair = (float*)alloc(NB * 320 * 4);
    float* h1 = (float*)alloc(NB * 1024 * 4);
    float* h2 = (float*)alloc(NB * 1024 * 4);
    float* h3 = (float*)alloc(NB * 512 * 4);

    // 1) dtype sniff
    sniff_kernel<<<1, 256, 0, stream>>>((const unsigned short*)fc2W, flag);

    // 2) parameter conversion
    CvtJob job;
    int si = 0;
    auto add = [&](const void* s, float* d, int n) { job.src[si] = s; job.dst[si] = d; job.n[si] = n; si++; };
    add(db1, db1f, 40); add(db2, db2f, 80); add(db3, db3f, 160);
    add(pb1, pb1f, 40); add(pb2, pb2f, 80); add(pb3, pb3f, 160);
    add(dattb, dattbF, 160); add(pattb, pattbF, 160); add(attb, attbF, 160);
    add(fc1b, fc1bF, 1024); add(fc2b, fc2bF, 1024); add(fc3b, fc3bF, 512);
    add(outb, outbF, 2);
    add(drug_emb, embDF, 65 * 64); add(prot_emb, embPF, 26 * 64);
    megacvt<<<dim3(17, NSEG), 256, 0, stream>>>(job, flag);
    cvt_wT<<<40, 256, 0, stream>>>(dW1, dW1t, 40, 256, flag);
    cvt_wT<<<40, 256, 0, stream>>>(pW1, pW1t, 40, 256, flag);
    pack_wmfma<<<192, 256, 0, stream>>>(dW2, dW2p, 80, 40, 6, 128, 64, flag);
    pack_wmfma<<<576, 256, 0, stream>>>(dW3, dW3p, 160, 80, 8, 192, 96, flag);
    pack_wmfma<<<256, 256, 0, stream>>>(pW2, pW2p, 80, 40, 8, 128, 64, flag);
    pack_wmfma<<<864, 256, 0, stream>>>(pW3, pW3p, 160, 80, 12, 192, 96, flag);
    cvt160b<<<dim3(100, 3), 256, 0, stream>>>(dattW, pattW, attW, dattWB, pattWB, wattB, flag);
    zero_init<<<(NB * 49 * 160 + 255) / 256, 256, 0, stream>>>(pair, Md);

    // 3) CNN stacks: conv1 VALU, conv2/3 MFMA
    conv1_both<<<16 + 16 * 19, 256, 0, stream>>>(drug_tok, prot_tok, embDF, embPF,
                                                 dW1t, pW1t, db1f, pb1f, d1, p1);
    conv_mfma<6, 40, 2><<<dim3(16, 2), 256, 0, stream>>>(d1, dW2p, db2f, d2, 61, 56, 80, 128, 1);
    conv_mfma<8, 40, 2><<<dim3(16 * 19, 2), 256, 0, stream>>>(p1, pW2p, pb2f, p2, 1197, 1190, 80, 128, 19);
    conv_mfma<8, 80, 3><<<dim3(16, 3), 256, 0, stream>>>(d2, dW3p, db3f, dcB, 56, 49, 160, 192, 1);
    conv_mfma<12, 80, 3><<<dim3(16 * 19, 3), 256, 0, stream>>>(p2, pW3p, pb3f, pcB, 1190, 1179, 160, 192, 19);

    // 4) attention projections (MFMA)
    att_proj_mfma<<<dim3(16 + 304, 3), 256, 0, stream>>>(dcB, pcB, dattWB, pattWB,
                                                         dattbF, pattbF, datt, pattB);

    // 5) pairwise relu-means
    mean_both<<<592 + 384, 192, 0, stream>>>(datt, pattB, MpW, Md);

    // 6) fused attW-GEMM + sigmoid + scale + maxpool (MFMA)
    att_sig_mfma<<<dim3(16 + 304, 3), 256, 0, stream>>>(Md, MpW, wattB, attbF, dcB, pcB, pair);

    // 7) MLP head
    lin_leaky<<<(NB * 1024 + 255) / 256, 256, 0, stream>>>(pair, fc1W, fc1bF, h1, 320, 1024, flag);
    lin_leaky<<<(NB * 1024 + 255) / 256, 256, 0, stream>>>(h1, fc2W, fc2bF, h2, 1024, 1024, flag);
    lin_leaky<<<(NB * 512 + 255) / 256, 256, 0, stream>>>(h2, fc3W, fc3bF, h3, 1024, 512, flag);
    out_layer<<<1, 64, 0, stream>>>(h3, outW, outbF, d_out, flag);
}

// Round 9
// 330.814 us; speedup vs baseline: 2.7659x; 1.3008x over previous
//
#include <hip/hip_runtime.h>
#include <hip/hip_bf16.h>

typedef __hip_bfloat16 bf16;
typedef __attribute__((ext_vector_type(8))) short short8;
typedef __attribute__((ext_vector_type(4))) float floatx4;

#define NB 16

// drug conv chain:  L 64 ->61(K4,C40) ->56(K6,C80) ->49(K8,C160)
// prot conv chain:  L 1200 ->1197(K4,C40) ->1190(K8,C80) ->1179(K12,C160)

__device__ __forceinline__ float b2f(bf16 x) { return __bfloat162float(x); }
__device__ __forceinline__ float u16bf(unsigned short u) {
    return __uint_as_float(((unsigned)u) << 16);
}
__device__ __forceinline__ unsigned short f2bu(float v) {
    union { bf16 h; unsigned short u; } cv;
    cv.h = __float2bfloat16(v);
    return cv.u;
}

// ---------------- dtype sniffer (R4-proven) ----------------
__global__ void sniff_kernel(const unsigned short* __restrict__ w, int* __restrict__ flag) {
    __shared__ int cnt;
    if (threadIdx.x == 0) cnt = 0;
    __syncthreads();
    int hits = 0;
    for (int s = 0; s < 4; s++) {
        unsigned short u = w[(threadIdx.x * 4 + s) * 2];
        float v = fabsf(u16bf(u));
        if (v > 1e-6f && v < 2.0f) hits++;
    }
    atomicAdd(&cnt, hits);
    __syncthreads();
    if (threadIdx.x == 0) *flag = (cnt > 512) ? 1 : 0;
}

// ---------------- conversions ----------------
#define NSEG 15
struct CvtJob {
    const void* src[NSEG];
    float* dst[NSEG];
    int n[NSEG];
};

__global__ void megacvt(CvtJob job, const int* __restrict__ flagp) {
    int seg = blockIdx.y;
    int i = blockIdx.x * 256 + threadIdx.x;
    if (i >= job.n[seg]) return;
    float v = (*flagp) ? b2f(((const bf16*)job.src[seg])[i])
                       : ((const float*)job.src[seg])[i];
    job.dst[seg][i] = v;
}

// conv weights [Cout][CIN][K] -> f32 [ci*K+k][Cout]  (conv1 only)
__global__ void cvt_wT(const void* __restrict__ src, float* __restrict__ dst,
                       int Cout, int CK, const int* __restrict__ flagp) {
    int i = blockIdx.x * 256 + threadIdx.x;
    if (i >= Cout * CK) return;
    int co = i / CK, r = i - co * CK;
    float v = (*flagp) ? b2f(((const bf16*)src)[i]) : ((const float*)src)[i];
    dst[r * Cout + co] = v;
}

// conv weights [Cout][CIN][K] -> bf16 MFMA pack [k][coP][CIP] (zero-padded)
__global__ void pack_wmfma(const void* __restrict__ src, bf16* __restrict__ dst,
                           int Cout, int CIN, int K, int coP, int CIP,
                           const int* __restrict__ flagp) {
    int i = blockIdx.x * 256 + threadIdx.x;
    int total = K * coP * CIP;
    if (i >= total) return;
    int ci = i % CIP;
    int t = i / CIP;
    int co = t % coP;
    int k = t / coP;
    float v = 0.f;
    if (co < Cout && ci < CIN) {
        int s = (co * CIN + ci) * K + k;
        v = (*flagp) ? b2f(((const bf16*)src)[s]) : ((const float*)src)[s];
    }
    dst[i] = __float2bfloat16(v);
}

// [160,160] (o,c) -> bf16 [o][c] (A-operand layout), 3 matrices
__global__ void cvt160b(const void* s0, const void* s1, const void* s2,
                        bf16* d0, bf16* d1, bf16* d2, const int* __restrict__ flagp) {
    int i = blockIdx.x * 256 + threadIdx.x;
    if (i >= 25600) return;
    const void* s = blockIdx.y == 0 ? s0 : (blockIdx.y == 1 ? s1 : s2);
    bf16* d = blockIdx.y == 0 ? d0 : (blockIdx.y == 1 ? d1 : d2);
    float v = (*flagp) ? b2f(((const bf16*)s)[i]) : ((const float*)s)[i];
    d[i] = __float2bfloat16(v);
}

__global__ void zero_init(float* __restrict__ pair, float* __restrict__ Md) {
    int i = blockIdx.x * 256 + threadIdx.x;
    if (i < NB * 320) pair[i] = 0.f;
    if (i < NB * 49 * 160) Md[i] = 0.f;
}

// ---------------- conv via MFMA implicit GEMM (R7-proven) ----------------
template <int K, int CIN, int CHUNKS>
__global__ __launch_bounds__(256) void conv_mfma(const bf16* __restrict__ x,
                                                 const bf16* __restrict__ Wp,
                                                 const float* __restrict__ bias,
                                                 bf16* __restrict__ y,
                                                 int Lin, int Lout, int Cout,
                                                 int coP, int tilesL) {
    const int CIP = CHUNKS * 32;
    const int PCI = CIP + 8;
    const int TLX = 64 + K - 1;
    __shared__ __align__(16) unsigned short xT[TLX * PCI];
    int b = blockIdx.x / tilesL;
    int l0 = (blockIdx.x % tilesL) << 6;
    const unsigned short* xb = (const unsigned short*)x + (size_t)b * CIN * Lin;
    for (int i = threadIdx.x; i < TLX * CIP; i += 256) {
        int ci = i / TLX, l = i - ci * TLX;
        unsigned short v = 0;
        int gl = l0 + l;
        if (ci < CIN && gl < Lin) v = xb[ci * Lin + gl];
        xT[l * PCI + ci] = v;
    }
    __syncthreads();
    int lane = threadIdx.x & 63;
    int w = threadIdx.x >> 6;
    int ct = blockIdx.y * 4 + w;
    int n = lane & 15, quad = lane >> 4;
    floatx4 acc[4];
#pragma unroll
    for (int i = 0; i < 4; i++) acc[i] = (floatx4){0.f, 0.f, 0.f, 0.f};
    const unsigned short* wbase = (const unsigned short*)Wp;
#pragma unroll
    for (int k = 0; k < K; k++) {
#pragma unroll
        for (int ch = 0; ch < CHUNKS; ch++) {
            short8 a = *(const short8*)(wbase +
                        ((size_t)(k * coP + ct * 16 + n)) * CIP + ch * 32 + quad * 8);
#pragma unroll
            for (int nt = 0; nt < 4; nt++) {
                short8 bb = *(const short8*)(xT + (nt * 16 + n + k) * PCI + ch * 32 + quad * 8);
                acc[nt] = __builtin_amdgcn_mfma_f32_16x16x32_bf16(a, bb, acc[nt], 0, 0, 0);
            }
        }
    }
    int m0 = quad * 4;
#pragma unroll
    for (int nt = 0; nt < 4; nt++) {
        int l = l0 + nt * 16 + n;
        if (l >= Lout) continue;
#pragma unroll
        for (int r = 0; r < 4; r++) {
            int co = ct * 16 + m0 + r;
            if (co < Cout)
                y[((size_t)b * Cout + co) * Lout + l] =
                    __float2bfloat16(fmaxf(acc[nt][r] + bias[co], 0.f));
        }
    }
}

// ---------------- conv1 (embedding-fused), drug+prot (R6-proven) ----------------
__global__ __launch_bounds__(256) void conv1_both(const int* __restrict__ dtok,
                                                  const int* __restrict__ ptok,
                                                  const float* __restrict__ embD,
                                                  const float* __restrict__ embP,
                                                  const float* __restrict__ dW1t,
                                                  const float* __restrict__ pW1t,
                                                  const float* __restrict__ db1f,
                                                  const float* __restrict__ pb1f,
                                                  bf16* __restrict__ d1,
                                                  bf16* __restrict__ p1) {
    const int K = 4, CIN = 64, TLX = 67, CPT = 10, Cout = 40;
    __shared__ float xs[CIN * TLX];
    __shared__ int stok[TLX];
    bool isD = blockIdx.x < 16;
    int b, l0, Lin, Lout;
    const int* tok; const float* embF; const float* wT; const float* bias; bf16* y;
    if (isD) {
        b = blockIdx.x; l0 = 0; Lin = 64; Lout = 61;
        tok = dtok; embF = embD; wT = dW1t; bias = db1f; y = d1;
    } else {
        int bx = blockIdx.x - 16;
        b = bx / 19; l0 = (bx % 19) << 6; Lin = 1200; Lout = 1197;
        tok = ptok; embF = embP; wT = pW1t; bias = pb1f; y = p1;
    }
    if (threadIdx.x < TLX) {
        int l = l0 + threadIdx.x;
        stok[threadIdx.x] = (l < Lin) ? tok[b * Lin + l] : -1;
    }
    __syncthreads();
    for (int i = threadIdx.x; i < CIN * TLX; i += 256) {
        int ci = i / TLX, j = i - ci * TLX;
        int t = stok[j];
        xs[i] = (t >= 0) ? embF[t * 64 + ci] : 0.f;
    }
    __syncthreads();
    int li = threadIdx.x & 63;
    int cg = __builtin_amdgcn_readfirstlane(threadIdx.x >> 6);
    int co0 = cg * CPT;
    float acc[CPT];
#pragma unroll
    for (int c = 0; c < CPT; c++) acc[c] = bias[co0 + c];
    for (int ci = 0; ci < CIN; ci++) {
        float xa[K];
        const float* xr = xs + ci * TLX + li;
#pragma unroll
        for (int t = 0; t < K; t++) xa[t] = xr[t];
        const float* wr = wT + (size_t)(ci * K) * Cout + co0;
#pragma unroll
        for (int k = 0; k < K; k++) {
#pragma unroll
            for (int c = 0; c < CPT; c++) acc[c] += xa[k] * wr[k * Cout + c];
        }
    }
    int l = l0 + li;
    if (l < Lout) {
#pragma unroll
        for (int c = 0; c < CPT; c++)
            y[((size_t)b * Cout + co0 + c) * Lout + l] = __float2bfloat16(fmaxf(acc[c], 0.f));
    }
}

// ---------------- attention projection via MFMA (R8-proven) ----------------
__global__ __launch_bounds__(256) void att_proj_mfma(const bf16* __restrict__ dcB,
                                                     const bf16* __restrict__ pcB,
                                                     const bf16* __restrict__ dWB,
                                                     const bf16* __restrict__ pWB,
                                                     const float* __restrict__ dbF,
                                                     const float* __restrict__ pbF,
                                                     float* __restrict__ datt,
                                                     bf16* __restrict__ pattB) {
    const int PCI = 168;
    __shared__ __align__(16) unsigned short xT[64 * PCI];
    bool isD = blockIdx.x < 16;
    int b, l0, L;
    const unsigned short* xsrc; const unsigned short* W; const float* bias;
    if (isD) {
        b = blockIdx.x; l0 = 0; L = 49;
        xsrc = (const unsigned short*)dcB; W = (const unsigned short*)dWB; bias = dbF;
    } else {
        int bx = blockIdx.x - 16;
        b = bx / 19; l0 = (bx % 19) << 6; L = 1179;
        xsrc = (const unsigned short*)pcB; W = (const unsigned short*)pWB; bias = pbF;
    }
    const unsigned short* xb = xsrc + (size_t)b * 160 * L;
    for (int i = threadIdx.x; i < 160 * 64; i += 256) {
        int c = i >> 6, j = i & 63;
        int l = l0 + j;
        xT[j * PCI + c] = (l < L) ? xb[(size_t)c * L + l] : (unsigned short)0;
    }
    __syncthreads();
    int lane = threadIdx.x & 63;
    int w = threadIdx.x >> 6;
    int t = blockIdx.y * 4 + w;
    int n = lane & 15, quad = lane >> 4;
    if (t >= 10) return;
    floatx4 acc[4];
#pragma unroll
    for (int i = 0; i < 4; i++) acc[i] = (floatx4){0.f, 0.f, 0.f, 0.f};
#pragma unroll
    for (int ch = 0; ch < 5; ch++) {
        short8 a = *(const short8*)(W + ((size_t)(t * 16 + n)) * 160 + ch * 32 + quad * 8);
#pragma unroll
        for (int nt = 0; nt < 4; nt++) {
            short8 bb = *(const short8*)(xT + (nt * 16 + n) * PCI + ch * 32 + quad * 8);
            acc[nt] = __builtin_amdgcn_mfma_f32_16x16x32_bf16(a, bb, acc[nt], 0, 0, 0);
        }
    }
    int m0 = quad * 4;
    int o0 = t * 16 + m0;
#pragma unroll
    for (int nt = 0; nt < 4; nt++) {
        int l = l0 + nt * 16 + n;
        if (l >= L) continue;
        if (isD) {
            float4 v;
            v.x = acc[nt][0] + bias[o0 + 0];
            v.y = acc[nt][1] + bias[o0 + 1];
            v.z = acc[nt][2] + bias[o0 + 2];
            v.w = acc[nt][3] + bias[o0 + 3];
            *(float4*)(datt + ((size_t)b * 49 + l) * 160 + o0) = v;
        } else {
            ushort4 u;
            u.x = f2bu(acc[nt][0] + bias[o0 + 0]);
            u.y = f2bu(acc[nt][1] + bias[o0 + 1]);
            u.z = f2bu(acc[nt][2] + bias[o0 + 2]);
            u.w = f2bu(acc[nt][3] + bias[o0 + 3]);
            *(ushort4*)((unsigned short*)pattB + ((size_t)b * 1179 + l) * 160 + o0) = u;
        }
    }
}

// ---------------- fused means: one relu(d+p) pass feeds Mp AND Md ----------------
// grid 16*37, block 192 (160 active). r = relu(dv[d]+pv) -> s (Mp row) + a[d] (Md).
__global__ __launch_bounds__(192) void mean_fused(const float* __restrict__ datt,
                                                  const bf16* __restrict__ patt,
                                                  bf16* __restrict__ MpW,
                                                  float* __restrict__ Md) {
    int k = threadIdx.x;
    if (k >= 160) return;
    int b = blockIdx.x / 37;
    int p0 = (blockIdx.x % 37) * 32;
    float dv[49], a[49];
#pragma unroll
    for (int d = 0; d < 49; d++) {
        dv[d] = datt[((size_t)b * 49 + d) * 160 + k];
        a[d] = 0.f;
    }
#pragma unroll 2
    for (int pi = 0; pi < 32; pi++) {
        int p = p0 + pi;
        float pv = (p < 1179) ? b2f(patt[((size_t)b * 1179 + p) * 160 + k]) : -1e30f;
        float s = 0.f;
#pragma unroll
        for (int d = 0; d < 49; d++) {
            float r = fmaxf(dv[d] + pv, 0.f);
            s += r;
            a[d] += r;
        }
        MpW[((size_t)b * 1184 + p) * 160 + k] = __float2bfloat16(s * (1.f / 49.f));
    }
#pragma unroll
    for (int d = 0; d < 49; d++)
        atomicAdd(Md + ((size_t)b * 49 + d) * 160 + k, a[d]);
}

// ---------------- att_sig via MFMA + fused sigmoid/scale/maxpool (R8-proven) ----------------
__global__ __launch_bounds__(256) void att_sig_mfma(const float* __restrict__ Md,
                                                    const bf16* __restrict__ MpW,
                                                    const bf16* __restrict__ wattB,
                                                    const float* __restrict__ attbF,
                                                    const bf16* __restrict__ dcB,
                                                    const bf16* __restrict__ pcB,
                                                    float* __restrict__ pair) {
    const int PCI = 168;
    __shared__ __align__(16) unsigned short sM[64 * PCI];
    bool isD = blockIdx.x < 16;
    int b, p0, L, off;
    const unsigned short* conv;
    if (isD) {
        b = blockIdx.x; p0 = 0; L = 49; off = 0; conv = (const unsigned short*)dcB;
        for (int i = threadIdx.x; i < 160 * 64; i += 256) {
            int r = i / 160, k = i - r * 160;
            float v = (r < 49) ? Md[((size_t)b * 49 + r) * 160 + k] * (1.f / 1179.f) : 0.f;
            sM[r * PCI + k] = f2bu(v);
        }
    } else {
        int bx = blockIdx.x - 16;
        b = bx / 19; p0 = (bx % 19) << 6; L = 1179; off = 160;
        conv = (const unsigned short*)pcB;
        const unsigned short* mb = (const unsigned short*)MpW + (size_t)b * 1184 * 160;
        for (int i = threadIdx.x; i < 160 * 64; i += 256) {
            int r = i / 160, k = i - r * 160;
            int p = p0 + r;
            sM[r * PCI + k] = (p < 1184) ? mb[(size_t)p * 160 + k] : (unsigned short)0;
        }
    }
    __syncthreads();
    int lane = threadIdx.x & 63;
    int w = threadIdx.x >> 6;
    int t = blockIdx.y * 4 + w;
    int n = lane & 15, quad = lane >> 4;
    if (t >= 10) return;
    floatx4 acc[4];
#pragma unroll
    for (int i = 0; i < 4; i++) acc[i] = (floatx4){0.f, 0.f, 0.f, 0.f};
    const unsigned short* W = (const unsigned short*)wattB;
#pragma unroll
    for (int ch = 0; ch < 5; ch++) {
        short8 a = *(const short8*)(W + ((size_t)(t * 16 + n)) * 160 + ch * 32 + quad * 8);
#pragma unroll
        for (int nt = 0; nt < 4; nt++) {
            short8 bb = *(const short8*)(sM + (nt * 16 + n) * PCI + ch * 32 + quad * 8);
            acc[nt] = __builtin_amdgcn_mfma_f32_16x16x32_bf16(a, bb, acc[nt], 0, 0, 0);
        }
    }
    int m0 = quad * 4;
    float vmax[4] = {0.f, 0.f, 0.f, 0.f};
#pragma unroll
    for (int nt = 0; nt < 4; nt++) {
        int p = p0 + nt * 16 + n;
#pragma unroll
        for (int r = 0; r < 4; r++) {
            int o = t * 16 + m0 + r;
            float sig = 1.f / (1.f + __expf(-(acc[nt][r] + attbF[o])));
            float v = 0.f;
            if (p < L) v = u16bf(conv[((size_t)b * 160 + o) * L + p]) * (0.5f + sig);
            vmax[r] = fmaxf(vmax[r], v);
        }
    }
#pragma unroll
    for (int m = 1; m < 16; m <<= 1) {
#pragma unroll
        for (int r = 0; r < 4; r++)
            vmax[r] = fmaxf(vmax[r], __shfl_xor(vmax[r], m, 64));
    }
    if (n == 0) {
#pragma unroll
        for (int r = 0; r < 4; r++)
            atomicMax((unsigned int*)(pair + b * 320 + off + t * 16 + m0 + r),
                      __float_as_uint(vmax[r]));
    }
}

// ---------------- MLP: block-per-output GEMV, 4 waves x 4 batches ----------------
// grid = OUT blocks, block 256. Lanes stride K with ushort4/float4; shuffle-reduce.
__global__ __launch_bounds__(256) void fc_block(const float* __restrict__ in,
                                                const void* __restrict__ W,
                                                const float* __restrict__ bias,
                                                float* __restrict__ out,
                                                int IN, int OUT,
                                                const int* __restrict__ flagp) {
    int j = blockIdx.x;
    int w = threadIdx.x >> 6, li = threadIdx.x & 63;
    int nv = IN >> 2;
    const float4* i0 = (const float4*)(in + (size_t)(w * 4 + 0) * IN);
    const float4* i1 = (const float4*)(in + (size_t)(w * 4 + 1) * IN);
    const float4* i2 = (const float4*)(in + (size_t)(w * 4 + 2) * IN);
    const float4* i3 = (const float4*)(in + (size_t)(w * 4 + 3) * IN);
    float p0 = 0.f, p1 = 0.f, p2 = 0.f, p3 = 0.f;
    if (*flagp) {
        const ushort4* w4 = (const ushort4*)((const unsigned short*)W + (size_t)j * IN);
        for (int v = li; v < nv; v += 64) {
            ushort4 u = w4[v];
            float wa = u16bf(u.x), wb = u16bf(u.y), wc = u16bf(u.z), wd = u16bf(u.w);
            float4 x;
            x = i0[v]; p0 += x.x * wa + x.y * wb + x.z * wc + x.w * wd;
            x = i1[v]; p1 += x.x * wa + x.y * wb + x.z * wc + x.w * wd;
            x = i2[v]; p2 += x.x * wa + x.y * wb + x.z * wc + x.w * wd;
            x = i3[v]; p3 += x.x * wa + x.y * wb + x.z * wc + x.w * wd;
        }
    } else {
        const float4* w4 = (const float4*)((const float*)W + (size_t)j * IN);
        for (int v = li; v < nv; v += 64) {
            float4 u = w4[v];
            float4 x;
            x = i0[v]; p0 += x.x * u.x + x.y * u.y + x.z * u.z + x.w * u.w;
            x = i1[v]; p1 += x.x * u.x + x.y * u.y + x.z * u.z + x.w * u.w;
            x = i2[v]; p2 += x.x * u.x + x.y * u.y + x.z * u.z + x.w * u.w;
            x = i3[v]; p3 += x.x * u.x + x.y * u.y + x.z * u.z + x.w * u.w;
        }
    }
#pragma unroll
    for (int m = 1; m < 64; m <<= 1) {
        p0 += __shfl_xor(p0, m, 64);
        p1 += __shfl_xor(p1, m, 64);
        p2 += __shfl_xor(p2, m, 64);
        p3 += __shfl_xor(p3, m, 64);
    }
    if (li == 0) {
        float bj = bias[j];
        float o0 = p0 + bj, o1 = p1 + bj, o2 = p2 + bj, o3 = p3 + bj;
        o0 = o0 > 0.f ? o0 : 0.01f * o0;
        o1 = o1 > 0.f ? o1 : 0.01f * o1;
        o2 = o2 > 0.f ? o2 : 0.01f * o2;
        o3 = o3 > 0.f ? o3 : 0.01f * o3;
        out[(size_t)(w * 4 + 0) * OUT + j] = o0;
        out[(size_t)(w * 4 + 1) * OUT + j] = o1;
        out[(size_t)(w * 4 + 2) * OUT + j] = o2;
        out[(size_t)(w * 4 + 3) * OUT + j] = o3;
    }
}

// final layer: grid 2 (j = output class), same structure, dtype-branched store
__global__ __launch_bounds__(256) void out_block(const float* __restrict__ h,
                                                 const void* __restrict__ W,
                                                 const float* __restrict__ biasF,
                                                 void* __restrict__ out,
                                                 const int* __restrict__ flagp) {
    int j = blockIdx.x;
    int w = threadIdx.x >> 6, li = threadIdx.x & 63;
    const int IN = 512, nv = 128;
    const float4* i0 = (const float4*)(h + (size_t)(w * 4 + 0) * IN);
    const float4* i1 = (const float4*)(h + (size_t)(w * 4 + 1) * IN);
    const float4* i2 = (const float4*)(h + (size_t)(w * 4 + 2) * IN);
    const float4* i3 = (const float4*)(h + (size_t)(w * 4 + 3) * IN);
    float p0 = 0.f, p1 = 0.f, p2 = 0.f, p3 = 0.f;
    int flag = *flagp;
    if (flag) {
        const ushort4* w4 = (const ushort4*)((const unsigned short*)W + (size_t)j * IN);
        for (int v = li; v < nv; v += 64) {
            ushort4 u = w4[v];
            float wa = u16bf(u.x), wb = u16bf(u.y), wc = u16bf(u.z), wd = u16bf(u.w);
            float4 x;
            x = i0[v]; p0 += x.x * wa + x.y * wb + x.z * wc + x.w * wd;
            x = i1[v]; p1 += x.x * wa + x.y * wb + x.z * wc + x.w * wd;
            x = i2[v]; p2 += x.x * wa + x.y * wb + x.z * wc + x.w * wd;
            x = i3[v]; p3 += x.x * wa + x.y * wb + x.z * wc + x.w * wd;
        }
    } else {
        const float4* w4 = (const float4*)((const float*)W + (size_t)j * IN);
        for (int v = li; v < nv; v += 64) {
            float4 u = w4[v];
            float4 x;
            x = i0[v]; p0 += x.x * u.x + x.y * u.y + x.z * u.z + x.w * u.w;
            x = i1[v]; p1 += x.x * u.x + x.y * u.y + x.z * u.z + x.w * u.w;
            x = i2[v]; p2 += x.x * u.x + x.y * u.y + x.z * u.z + x.w * u.w;
            x = i3[v]; p3 += x.x * u.x + x.y * u.y + x.z * u.z + x.w * u.w;
        }
    }
#pragma unroll
    for (int m = 1; m < 64; m <<= 1) {
        p0 += __shfl_xor(p0, m, 64);
        p1 += __shfl_xor(p1, m, 64);
        p2 += __shfl_xor(p2, m, 64);
        p3 += __shfl_xor(p3, m, 64);
    }
    if (li == 0) {
        float bj = biasF[j];
        float o0 = p0 + bj, o1 = p1 + bj, o2 = p2 + bj, o3 = p3 + bj;
        if (flag) {
            bf16* ob = (bf16*)out;
            ob[(w * 4 + 0) * 2 + j] = __float2bfloat16(o0);
            ob[(w * 4 + 1) * 2 + j] = __float2bfloat16(o1);
            ob[(w * 4 + 2) * 2 + j] = __float2bfloat16(o2);
            ob[(w * 4 + 3) * 2 + j] = __float2bfloat16(o3);
        } else {
            float* of = (float*)out;
            of[(w * 4 + 0) * 2 + j] = o0;
            of[(w * 4 + 1) * 2 + j] = o1;
            of[(w * 4 + 2) * 2 + j] = o2;
            of[(w * 4 + 3) * 2 + j] = o3;
        }
    }
}

extern "C" void kernel_launch(void* const* d_in, const int* in_sizes, int n_in,
                              void* d_out, int out_size, void* d_ws, size_t ws_size,
                              hipStream_t stream) {
    const int* drug_tok = (const int*)d_in[0];
    const int* prot_tok = (const int*)d_in[1];
    const void* drug_emb = d_in[2];
    const void* prot_emb = d_in[3];
    const void* dW1 = d_in[4];  const void* db1 = d_in[5];
    const void* dW2 = d_in[6];  const void* db2 = d_in[7];
    const void* dW3 = d_in[8];  const void* db3 = d_in[9];
    const void* pW1 = d_in[10]; const void* pb1 = d_in[11];
    const void* pW2 = d_in[12]; const void* pb2 = d_in[13];
    const void* pW3 = d_in[14]; const void* pb3 = d_in[15];
    const void* dattW = d_in[16]; const void* dattb = d_in[17];
    const void* pattW = d_in[18]; const void* pattb = d_in[19];
    const void* attW  = d_in[20]; const void* attb  = d_in[21];
    const void* fc1W = d_in[22]; const void* fc1b = d_in[23];
    const void* fc2W = d_in[24]; const void* fc2b = d_in[25];
    const void* fc3W = d_in[26]; const void* fc3b = d_in[27];
    const void* outW = d_in[28]; const void* outb = d_in[29];

    char* base = (char*)d_ws;
    size_t cur = 0;
    auto alloc = [&](size_t bytes) -> char* {
        char* p = base + cur;
        cur = (cur + bytes + 255) & ~(size_t)255;
        return p;
    };
    int*   flag  = (int*)alloc(256);
    float* embDF = (float*)alloc(65 * 64 * 4);
    float* embPF = (float*)alloc(26 * 64 * 4);
    float* dW1t = (float*)alloc(10240 * 4);
    float* pW1t = (float*)alloc(10240 * 4);
    bf16* dW2p = (bf16*)alloc((size_t)6 * 128 * 64 * 2);
    bf16* dW3p = (bf16*)alloc((size_t)8 * 192 * 96 * 2);
    bf16* pW2p = (bf16*)alloc((size_t)8 * 128 * 64 * 2);
    bf16* pW3p = (bf16*)alloc((size_t)12 * 192 * 96 * 2);
    float* db1f = (float*)alloc(40 * 4);
    float* db2f = (float*)alloc(80 * 4);
    float* db3f = (float*)alloc(160 * 4);
    float* pb1f = (float*)alloc(40 * 4);
    float* pb2f = (float*)alloc(80 * 4);
    float* pb3f = (float*)alloc(160 * 4);
    float* dattbF = (float*)alloc(160 * 4);
    float* pattbF = (float*)alloc(160 * 4);
    float* attbF  = (float*)alloc(160 * 4);
    float* fc1bF = (float*)alloc(1024 * 4);
    float* fc2bF = (float*)alloc(1024 * 4);
    float* fc3bF = (float*)alloc(512 * 4);
    float* outbF = (float*)alloc(2 * 4);
    bf16* dattWB = (bf16*)alloc(25600 * 2);
    bf16* pattWB = (bf16*)alloc(25600 * 2);
    bf16* wattB  = (bf16*)alloc(25600 * 2);
    bf16* d1  = (bf16*)alloc((size_t)NB * 40 * 61 * 2);
    bf16* d2  = (bf16*)alloc((size_t)NB * 80 * 56 * 2);
    bf16* dcB = (bf16*)alloc((size_t)NB * 160 * 49 * 2);
    bf16* p1  = (bf16*)alloc((size_t)NB * 40 * 1197 * 2);
    bf16* p2  = (bf16*)alloc((size_t)NB * 80 * 1190 * 2);
    bf16* pcB = (bf16*)alloc((size_t)NB * 160 * 1179 * 2);
    float* datt  = (float*)alloc((size_t)NB * 49 * 160 * 4);
    bf16* pattB = (bf16*)alloc((size_t)NB * 1179 * 160 * 2);
    float* Md   = (float*)alloc((size_t)NB * 49 * 160 * 4);
    bf16* MpW  = (bf16*)alloc((size_t)NB * 1184 * 160 * 2);
    float* pair = (float*)alloc(NB * 320 * 4);
    float* h1 = (float*)alloc(NB * 1024 * 4);
    float* h2 = (float*)alloc(NB * 1024 * 4);
    float* h3 = (float*)alloc(NB * 512 * 4);

    // 1) dtype sniff
    sniff_kernel<<<1, 256, 0, stream>>>((const unsigned short*)fc2W, flag);

    // 2) parameter conversion
    CvtJob job;
    int si = 0;
    auto add = [&](const void* s, float* d, int n) { job.src[si] = s; job.dst[si] = d; job.n[si] = n; si++; };
    add(db1, db1f, 40); add(db2, db2f, 80); add(db3, db3f, 160);
    add(pb1, pb1f, 40); add(pb2, pb2f, 80); add(pb3, pb3f, 160);
    add(dattb, dattbF, 160); add(pattb, pattbF, 160); add(attb, attbF, 160);
    add(fc1b, fc1bF, 1024); add(fc2b, fc2bF, 1024); add(fc3b, fc3bF, 512);
    add(outb, outbF, 2);
    add(drug_emb, embDF, 65 * 64); add(prot_emb, embPF, 26 * 64);
    megacvt<<<dim3(17, NSEG), 256, 0, stream>>>(job, flag);
    cvt_wT<<<40, 256, 0, stream>>>(dW1, dW1t, 40, 256, flag);
    cvt_wT<<<40, 256, 0, stream>>>(pW1, pW1t, 40, 256, flag);
    pack_wmfma<<<192, 256, 0, stream>>>(dW2, dW2p, 80, 40, 6, 128, 64, flag);
    pack_wmfma<<<576, 256, 0, stream>>>(dW3, dW3p, 160, 80, 8, 192, 96, flag);
    pack_wmfma<<<256, 256, 0, stream>>>(pW2, pW2p, 80, 40, 8, 128, 64, flag);
    pack_wmfma<<<864, 256, 0, stream>>>(pW3, pW3p, 160, 80, 12, 192, 96, flag);
    cvt160b<<<dim3(100, 3), 256, 0, stream>>>(dattW, pattW, attW, dattWB, pattWB, wattB, flag);
    zero_init<<<(NB * 49 * 160 + 255) / 256, 256, 0, stream>>>(pair, Md);

    // 3) CNN stacks: conv1 VALU, conv2/3 MFMA
    conv1_both<<<16 + 16 * 19, 256, 0, stream>>>(drug_tok, prot_tok, embDF, embPF,
                                                 dW1t, pW1t, db1f, pb1f, d1, p1);
    conv_mfma<6, 40, 2><<<dim3(16, 2), 256, 0, stream>>>(d1, dW2p, db2f, d2, 61, 56, 80, 128, 1);
    conv_mfma<8, 40, 2><<<dim3(16 * 19, 2), 256, 0, stream>>>(p1, pW2p, pb2f, p2, 1197, 1190, 80, 128, 19);
    conv_mfma<8, 80, 3><<<dim3(16, 3), 256, 0, stream>>>(d2, dW3p, db3f, dcB, 56, 49, 160, 192, 1);
    conv_mfma<12, 80, 3><<<dim3(16 * 19, 3), 256, 0, stream>>>(p2, pW3p, pb3f, pcB, 1190, 1179, 160, 192, 19);

    // 4) attention projections (MFMA)
    att_proj_mfma<<<dim3(16 + 304, 3), 256, 0, stream>>>(dcB, pcB, dattWB, pattWB,
                                                         dattbF, pattbF, datt, pattB);

    // 5) fused pairwise relu-means (single pass)
    mean_fused<<<16 * 37, 192, 0, stream>>>(datt, pattB, MpW, Md);

    // 6) fused attW-GEMM + sigmoid + scale + maxpool (MFMA)
    att_sig_mfma<<<dim3(16 + 304, 3), 256, 0, stream>>>(Md, MpW, wattB, attbF, dcB, pcB, pair);

    // 7) MLP head (block-per-output GEMV)
    fc_block<<<1024, 256, 0, stream>>>(pair, fc1W, fc1bF, h1, 320, 1024, flag);
    fc_block<<<1024, 256, 0, stream>>>(h1, fc2W, fc2bF, h2, 1024, 1024, flag);
    fc_block<<<512, 256, 0, stream>>>(h2, fc3W, fc3bF, h3, 1024, 512, flag);
    out_block<<<2, 256, 0, stream>>>(h3, outW, outbF, d_out, flag);
}